// Round 12
// baseline (3814.774 us; speedup 1.0000x reference)
//
#include <hip/hip_runtime.h>

#define NVV 100000
#define NSV 50000
#define E_VV 1600000
#define E_H  800000
#define E_IN 800000
#define E_SS 800000
#define ETOT 4000000
#define DIN 5
#define H_ROW 100000          // concatenated cnt/rs space: vv|h|in|ss
#define IN_ROW 150000
#define SS_ROW 200000
#define NROWS 250000
#define POS_H  E_VV
#define POS_IN (E_VV + E_H)
#define POS_SS (E_VV + E_H + E_IN)
#define NBUK 196              // vv buckets (dst >> 9)
#define NBUKS 98              // NSV-graph buckets
#define NBTOT 490             // vv|h|in|ss bucket space
#define BUK_H  196
#define BUK_IN 294
#define BUK_SS 392
#define BSHIFT 9
#define T1 4096               // edges per fill-stage-1 block
#define TC 16384              // edges per bucket-count block
#define G1VV 391              // ceil(E_VV/T1)
#define G1S  196              // ceil(E_H/T1)
#define SB1  (G1VV + 3 * G1S) // 979 fused stage-1 blocks

__device__ __forceinline__ unsigned short f2bf(float x) {
  unsigned b = __float_as_uint(x);
  return (unsigned short)((b + 0x7FFFu + ((b >> 16) & 1u)) >> 16);
}
__device__ __forceinline__ float bf2f(unsigned short u) {
  return __uint_as_float(((unsigned)u) << 16);
}

// ====================== CSR build: bucket counts -> bases -> fused binned fills ======================

__global__ __launch_bounds__(256)
void k_bucket_count(const int* __restrict__ d_vv, const int* __restrict__ d_h,
                    const int* __restrict__ d_in, const int* __restrict__ d_ss,
                    int* __restrict__ bcnt) {
  __shared__ int h[NBTOT];
  const int tid = threadIdx.x;
  for (int i = tid; i < NBTOT; i += 256) h[i] = 0;
  __syncthreads();
  const int base = blockIdx.x * TC;
#pragma unroll 4
  for (int k = 0; k < TC / 256; k++) {
    int e = base + k * 256 + tid;
    int bi = -1;
    if (e < E_VV) bi = d_vv[e] >> BSHIFT;
    else if (e < POS_IN) bi = BUK_H + (d_h[e - POS_H] >> BSHIFT);
    else if (e < POS_SS) bi = BUK_IN + (d_in[e - POS_IN] >> BSHIFT);
    else if (e < ETOT) bi = BUK_SS + (d_ss[e - POS_SS] >> BSHIFT);
    if (bi >= 0) atomicAdd(&h[bi], 1);
  }
  __syncthreads();
  for (int i = tid; i < NBTOT; i += 256) if (h[i]) atomicAdd(&bcnt[i], h[i]);
}

__global__ __launch_bounds__(512)
void k_bucket_scan(const int* __restrict__ bcnt, int* __restrict__ bbase, int* __restrict__ cb) {
  __shared__ int sd[512];
  int t = threadIdx.x;
  int v = (t < NBTOT) ? bcnt[t] : 0;
  sd[t] = v; __syncthreads();
  for (int off = 1; off < 512; off <<= 1) {
    int x = (t >= off) ? sd[t - off] : 0;
    __syncthreads();
    sd[t] += x;
    __syncthreads();
  }
  int segstart = (t < BUK_H) ? 0 : (t < BUK_IN) ? BUK_H : (t < BUK_SS) ? BUK_IN : BUK_SS;
  int excl = ((t > 0) ? sd[t - 1] : 0) - ((segstart > 0) ? sd[segstart - 1] : 0);
  if (t < NBTOT) { bbase[t] = excl; cb[t] = excl; }
}

// ---- fused stage 1: all 4 graphs, bucket-grouped binning, coalesced run writes ----
__global__ __launch_bounds__(256)
void k_fill_s1_all(const int* __restrict__ s_vv, const int* __restrict__ d_vv,
                   const int* __restrict__ et,
                   const int* __restrict__ s_h, const int* __restrict__ d_h,
                   const float* __restrict__ ew,
                   const int* __restrict__ s_in, const int* __restrict__ d_in,
                   const int* __restrict__ s_ss, const int* __restrict__ d_ss,
                   int* __restrict__ cb,
                   unsigned* __restrict__ temp_vv, uint2* __restrict__ temp_h,
                   unsigned* __restrict__ temp_in, unsigned* __restrict__ temp_ss) {
  __shared__ int hist[NBUK], lbase[NBUK], run[NBUK], gb[NBUK];
  __shared__ int sc[256];
  __shared__ unsigned stage[T1];
  __shared__ unsigned stageW[T1];
  __shared__ int gpos[T1];
  const int tid = threadIdx.x;
  const int b = blockIdx.x;
  int g, tile;
  if (b < G1VV) { g = 0; tile = b; }
  else if (b < G1VV + G1S) { g = 1; tile = b - G1VV; }
  else if (b < G1VV + 2 * G1S) { g = 2; tile = b - G1VV - G1S; }
  else { g = 3; tile = b - G1VV - 2 * G1S; }
  const int ne = (g == 0) ? E_VV : E_H;
  const int nbuk = (g == 0) ? NBUK : NBUKS;
  const int cboff = (g == 0) ? 0 : (g == 1) ? BUK_H : (g == 2) ? BUK_IN : BUK_SS;
  const int* S = (g == 0) ? s_vv : (g == 1) ? s_h : (g == 2) ? s_in : s_ss;
  const int* D = (g == 0) ? d_vv : (g == 1) ? d_h : (g == 2) ? d_in : d_ss;
  const int base = tile * T1;
  const int nvalid = min(T1, ne - base);
  for (int i = tid; i < nbuk; i += 256) { hist[i] = 0; run[i] = 0; }
  __syncthreads();
  int dv[16]; unsigned pk[16], pkw[16];
#pragma unroll
  for (int k = 0; k < 16; k++) {
    int e = base + k * 256 + tid;
    if (e - base < nvalid) {
      int d = D[e];
      dv[k] = d;
      if (g == 0) pk[k] = (unsigned)(((d & 511) << 19) | (et[e] << 17) | S[e]);
      else pk[k] = (unsigned)(((d & 511) << 17) | S[e]);
      if (g == 1) pkw[k] = (unsigned)__float_as_int(ew[e]);
      atomicAdd(&hist[d >> BSHIFT], 1);
    } else dv[k] = -1;
  }
  __syncthreads();
  int my = (tid < nbuk) ? hist[tid] : 0;
  sc[tid] = my; __syncthreads();
  for (int off = 1; off < 256; off <<= 1) {
    int t = (tid >= off) ? sc[tid - off] : 0;
    __syncthreads();
    sc[tid] += t;
    __syncthreads();
  }
  if (tid < nbuk) {
    lbase[tid] = sc[tid] - my;
    gb[tid] = my ? atomicAdd(&cb[cboff + tid], my) : 0;
  }
  __syncthreads();
#pragma unroll
  for (int k = 0; k < 16; k++) {
    if (dv[k] >= 0) {
      int bu = dv[k] >> BSHIFT;
      int loc = atomicAdd(&run[bu], 1);
      int li = lbase[bu] + loc;
      stage[li] = pk[k];
      if (g == 1) stageW[li] = pkw[k];
      gpos[li] = gb[bu] + loc;
    }
  }
  __syncthreads();
  if (g == 0)      for (int i = tid; i < nvalid; i += 256) temp_vv[gpos[i]] = stage[i];
  else if (g == 1) for (int i = tid; i < nvalid; i += 256) temp_h[gpos[i]] = make_uint2(stage[i], stageW[i]);
  else if (g == 2) for (int i = tid; i < nvalid; i += 256) temp_in[gpos[i]] = stage[i];
  else             for (int i = tid; i < nvalid; i += 256) temp_ss[gpos[i]] = stage[i];
}

// ---- fused stage 2 ----
__global__ __launch_bounds__(256)
void k_fill_s2_all(const unsigned* __restrict__ temp_vv, const uint2* __restrict__ temp_h,
                   const unsigned* __restrict__ temp_in, const unsigned* __restrict__ temp_ss,
                   const int* __restrict__ bbase,
                   unsigned* __restrict__ payload_vv, int2* __restrict__ eh,
                   int* __restrict__ srcs_in, int* __restrict__ srcs_ss,
                   int* __restrict__ rs_all, int* __restrict__ cnt_all,
                   const float* __restrict__ x, float4* __restrict__ xp,
                   float* __restrict__ dinvS) {
  __shared__ int lcnt[512], lpos[512];
  __shared__ int sc[256];
  const int b = blockIdx.x, tid = threadIdx.x;
  int g, lb;
  if (b < BUK_H) { g = 0; lb = b; }
  else if (b < BUK_IN) { g = 1; lb = b - BUK_H; }
  else if (b < BUK_SS) { g = 2; lb = b - BUK_IN; }
  else { g = 3; lb = b - BUK_SS; }
  const int d0 = lb << BSHIFT;
  const int nrows = (g == 0) ? NVV : NSV;
  const int rowbase = (g == 0) ? 0 : (g == 1) ? H_ROW : (g == 2) ? IN_ROW : SS_ROW;
  const int ne = (g == 0) ? E_VV : E_H;
  const int lastb = (g == 0) ? NBUK - 1 : NBUKS - 1;
  const int shift = (g == 0) ? 19 : 17;
  lcnt[tid] = 0; lcnt[tid + 256] = 0;
  __syncthreads();
  const int gstart = bbase[b];
  const int gend = (lb == lastb) ? ne : bbase[b + 1];
  if (g == 1) {
    for (int i = gstart + tid; i < gend; i += 256) atomicAdd(&lcnt[temp_h[i].x >> 17], 1);
  } else {
    const unsigned* tp = (g == 0) ? temp_vv : (g == 2) ? temp_in : temp_ss;
    for (int i = gstart + tid; i < gend; i += 256) atomicAdd(&lcnt[tp[i] >> shift], 1);
  }
  __syncthreads();
  int c0 = lcnt[2 * tid], c1 = lcnt[2 * tid + 1];
  int ps = c0 + c1;
  sc[tid] = ps; __syncthreads();
  for (int off = 1; off < 256; off <<= 1) {
    int x2 = (tid >= off) ? sc[tid - off] : 0;
    __syncthreads();
    sc[tid] += x2;
    __syncthreads();
  }
  int basep = gstart + sc[tid] - ps;
  lpos[2 * tid] = basep;
  lpos[2 * tid + 1] = basep + c0;
  __syncthreads();
  for (int d = tid; d < 512; d += 256) {
    int gd = d0 + d;
    if (gd < nrows) {
      rs_all[rowbase + gd] = lpos[d];
      cnt_all[rowbase + gd] = lcnt[d];
      if (g == 0) {
        float dc = (float)lcnt[d];
        float di = dc > 0.f ? rsqrtf(dc) : 0.f;
        const float* xr = x + (size_t)gd * 5;
        xp[gd * 2]     = make_float4(xr[0], xr[1], xr[2], xr[3]);
        xp[gd * 2 + 1] = make_float4(xr[4], di, 0.f, 0.f);
      } else if (g == 3) {
        float dc = (float)lcnt[d];
        dinvS[gd] = dc > 0.f ? rsqrtf(dc) : 0.f;
      }
    }
  }
  __syncthreads();
  if (g == 0) {
    for (int i = gstart + tid; i < gend; i += 256) {
      unsigned en = temp_vv[i];
      int pos = atomicAdd(&lpos[en >> 19], 1);
      payload_vv[pos] = en & 0x7FFFFu;
    }
  } else if (g == 1) {
    for (int i = gstart + tid; i < gend; i += 256) {
      uint2 en = temp_h[i];
      int pos = atomicAdd(&lpos[en.x >> 17], 1);
      eh[pos] = make_int2((int)(en.x & 0x1FFFFu), (int)en.y);
    }
  } else if (g == 2) {
    for (int i = gstart + tid; i < gend; i += 256) {
      unsigned en = temp_in[i];
      int pos = atomicAdd(&lpos[en >> 17], 1);
      srcs_in[pos] = (int)(en & 0x1FFFFu);
    }
  } else {
    for (int i = gstart + tid; i < gend; i += 256) {
      unsigned en = temp_ss[i];
      int pos = atomicAdd(&lpos[en >> 17], 1);
      srcs_ss[pos] = (int)(en & 0x1FFFFu);
    }
  }
}

// ====================== Phase A: v-graph (5-dim, padded rows) ======================

__global__ __launch_bounds__(256)
void k_vv_pass1(const float4* __restrict__ xp,
                const int* __restrict__ rowstart, const int* __restrict__ cnt,
                const unsigned* __restrict__ payload,
                float4* __restrict__ ra4all, float4* __restrict__ h1p) {
  int d = blockIdx.x * 256 + threadIdx.x;
  if (d >= NVV) return;
  int rs = rowstart[d], c = cnt[d];
  float a0[5] = {0,0,0,0,0}, a1[5] = {0,0,0,0,0}, a2[5] = {0,0,0,0,0}, h[5] = {0,0,0,0,0};
  float c0 = 0.f, c1 = 0.f, c2 = 0.f;
  int j = 0;
  for (; j + 2 <= c; j += 2) {
    unsigned pA = payload[rs + j], pB = payload[rs + j + 1];
    int sA = pA & 0x1FFFF, rA = pA >> 17;
    int sB = pB & 0x1FFFF, rB = pB >> 17;
    float4 xA0 = xp[sA * 2], xA1 = xp[sA * 2 + 1];
    float4 xB0 = xp[sB * 2], xB1 = xp[sB * 2 + 1];
    float xsA[5] = {xA0.x, xA0.y, xA0.z, xA0.w, xA1.x};
    float xsB[5] = {xB0.x, xB0.y, xB0.z, xB0.w, xB1.x};
    float wA = xA1.y, wB = xB1.y;
    float mA0 = (rA == 0) ? 1.f : 0.f, mA1 = (rA == 1) ? 1.f : 0.f, mA2 = (rA == 2) ? 1.f : 0.f;
    float mB0 = (rB == 0) ? 1.f : 0.f, mB1 = (rB == 1) ? 1.f : 0.f, mB2 = (rB == 2) ? 1.f : 0.f;
    c0 += mA0 + mB0; c1 += mA1 + mB1; c2 += mA2 + mB2;
#pragma unroll
    for (int k = 0; k < 5; k++) {
      h[k] += wA * xsA[k] + wB * xsB[k];
      a0[k] += mA0 * xsA[k] + mB0 * xsB[k];
      a1[k] += mA1 * xsA[k] + mB1 * xsB[k];
      a2[k] += mA2 * xsA[k] + mB2 * xsB[k];
    }
  }
  for (; j < c; j++) {
    unsigned p = payload[rs + j];
    int s = p & 0x1FFFF, r = p >> 17;
    float4 x0 = xp[s * 2], x1 = xp[s * 2 + 1];
    float xs[5] = {x0.x, x0.y, x0.z, x0.w, x1.x};
    float wsc = x1.y;
    float m0 = (r == 0) ? 1.f : 0.f, m1 = (r == 1) ? 1.f : 0.f, m2 = (r == 2) ? 1.f : 0.f;
    c0 += m0; c1 += m1; c2 += m2;
#pragma unroll
    for (int k = 0; k < 5; k++) {
      h[k] += wsc * xs[k];
      a0[k] += m0 * xs[k]; a1[k] += m1 * xs[k]; a2[k] += m2 * xs[k];
    }
  }
  float dv = xp[d * 2 + 1].y;
  float4* ra4 = ra4all + d * 5;
  ra4[0] = make_float4(a0[0], a0[1], a0[2], a0[3]);
  ra4[1] = make_float4(a0[4], a1[0], a1[1], a1[2]);
  ra4[2] = make_float4(a1[3], a1[4], a2[0], a2[1]);
  ra4[3] = make_float4(a2[2], a2[3], a2[4], c0);
  ra4[4] = make_float4(c1, c2, 0.f, 0.f);
  h1p[d * 2]     = make_float4(dv * h[0], dv * h[1], dv * h[2], dv * h[3]);
  h1p[d * 2 + 1] = make_float4(dv * h[4], dv, 0.f, 0.f);
}

__global__ __launch_bounds__(256)
void k_vv_hop(const float4* __restrict__ hinp,
              const int* __restrict__ rowstart, const int* __restrict__ cnt,
              const unsigned* __restrict__ payload, float4* __restrict__ houtp) {
  int d = blockIdx.x * 256 + threadIdx.x;
  if (d >= NVV) return;
  int rs = rowstart[d], c = cnt[d];
  float h[5] = {0,0,0,0,0};
  int j = 0;
  for (; j + 4 <= c; j += 4) {
    unsigned p0 = payload[rs + j], p1 = payload[rs + j + 1];
    unsigned p2 = payload[rs + j + 2], p3 = payload[rs + j + 3];
    int s0 = p0 & 0x1FFFF, s1 = p1 & 0x1FFFF, s2 = p2 & 0x1FFFF, s3 = p3 & 0x1FFFF;
    float4 a0 = hinp[s0 * 2], b0 = hinp[s0 * 2 + 1];
    float4 a1 = hinp[s1 * 2], b1 = hinp[s1 * 2 + 1];
    float4 a2 = hinp[s2 * 2], b2 = hinp[s2 * 2 + 1];
    float4 a3 = hinp[s3 * 2], b3 = hinp[s3 * 2 + 1];
    float w0 = b0.y, w1 = b1.y, w2 = b2.y, w3 = b3.y;
    h[0] += w0 * a0.x + w1 * a1.x + w2 * a2.x + w3 * a3.x;
    h[1] += w0 * a0.y + w1 * a1.y + w2 * a2.y + w3 * a3.y;
    h[2] += w0 * a0.z + w1 * a1.z + w2 * a2.z + w3 * a3.z;
    h[3] += w0 * a0.w + w1 * a1.w + w2 * a2.w + w3 * a3.w;
    h[4] += w0 * b0.x + w1 * b1.x + w2 * b2.x + w3 * b3.x;
  }
  for (; j < c; j++) {
    int s = payload[rs + j] & 0x1FFFF;
    float4 x0 = hinp[s * 2], x1 = hinp[s * 2 + 1];
    float wsc = x1.y;
    h[0] += wsc * x0.x; h[1] += wsc * x0.y; h[2] += wsc * x0.z; h[3] += wsc * x0.w;
    h[4] += wsc * x1.x;
  }
  float dv = hinp[d * 2 + 1].y;
  houtp[d * 2]     = make_float4(dv * h[0], dv * h[1], dv * h[2], dv * h[3]);
  houtp[d * 2 + 1] = make_float4(dv * h[4], dv, 0.f, 0.f);
}

// 8 nodes/thread, Ws column in 35 VGPRs, float4 relall loads.
__global__ __launch_bounds__(256)
void k_combine_gx(const float4* __restrict__ xp,
                  const float4* __restrict__ ra4all,
                  const float4* __restrict__ h1p, const float4* __restrict__ h2p,
                  const float4* __restrict__ h3p,
                  const float* __restrict__ W1_rel, const float* __restrict__ W1_root,
                  const float* __restrict__ b1,
                  const float* __restrict__ W12, const float* __restrict__ b12,
                  unsigned short* __restrict__ gx16) {
  __shared__ float Ws[7 * 320];
  __shared__ float bs[64];
  int tid = threadIdx.x;
  for (int i = tid; i < 320; i += 256) {
    Ws[i]        = W1_root[i] + W12[i];
    Ws[320 + i]  = W1_rel[i];
    Ws[640 + i]  = W1_rel[320 + i];
    Ws[960 + i]  = W1_rel[640 + i];
    Ws[1280 + i] = W12[320 + i];
    Ws[1600 + i] = W12[640 + i];
    Ws[1920 + i] = W12[960 + i];
  }
  if (tid < 64) bs[tid] = b1[tid] + b12[tid];
  __syncthreads();
  const int f = tid & 63;
  const int grp = tid >> 6;
  float wcol[35];
#pragma unroll
  for (int t = 0; t < 35; t++) wcol[t] = Ws[t * 64 + f];
  const float bias = bs[f];
  const int v0 = blockIdx.x * 32 + grp * 8;
  for (int n = 0; n < 8; n++) {
    int v = v0 + n;
    if (v >= NVV) return;
    float in[35];
    {
      float4 x0 = xp[v * 2], x1 = xp[v * 2 + 1];
      in[0] = x0.x; in[1] = x0.y; in[2] = x0.z; in[3] = x0.w; in[4] = x1.x;
    }
    {
      const float4* ra = ra4all + v * 5;
      float4 r0 = ra[0], r1 = ra[1], r2 = ra[2], r3 = ra[3], r4 = ra[4];
      float i0 = 1.0f / fmaxf(r3.w, 1.0f);
      float i1 = 1.0f / fmaxf(r4.x, 1.0f);
      float i2 = 1.0f / fmaxf(r4.y, 1.0f);
      in[5]  = r0.x * i0; in[6]  = r0.y * i0; in[7]  = r0.z * i0; in[8]  = r0.w * i0; in[9]  = r1.x * i0;
      in[10] = r1.y * i1; in[11] = r1.z * i1; in[12] = r1.w * i1; in[13] = r2.x * i1; in[14] = r2.y * i1;
      in[15] = r2.z * i2; in[16] = r2.w * i2; in[17] = r3.x * i2; in[18] = r3.y * i2; in[19] = r3.z * i2;
    }
    {
      float4 a = h1p[v * 2], b = h1p[v * 2 + 1];
      in[20] = a.x; in[21] = a.y; in[22] = a.z; in[23] = a.w; in[24] = b.x;
      a = h2p[v * 2]; b = h2p[v * 2 + 1];
      in[25] = a.x; in[26] = a.y; in[27] = a.z; in[28] = a.w; in[29] = b.x;
      a = h3p[v * 2]; b = h3p[v * 2 + 1];
      in[30] = a.x; in[31] = a.y; in[32] = a.z; in[33] = a.w; in[34] = b.x;
    }
    float acc = bias;
#pragma unroll
    for (int t = 0; t < 35; t++) acc += in[t] * wcol[t];
    gx16[v * 64 + f] = f2bf(acc);
  }
}

// ================= 64-dim CSR gathers (wave per dst, lane=feature, 8-way MLP) =================

__global__ __launch_bounds__(256)
void k_aggB(const unsigned short* __restrict__ X16,
            const int* __restrict__ rs_h, const int* __restrict__ cnt_h,
            const int2* __restrict__ eh,
            const int* __restrict__ rs_in, const int* __restrict__ cnt_in,
            const int* __restrict__ srcs_in,
            float* __restrict__ outw, float* __restrict__ outu, float* __restrict__ outIN,
            int nb64) {
  int bb = blockIdx.x;
  int lane = threadIdx.x & 63;
  if (bb < nb64) {
    int wid = bb * 4 + (threadIdx.x >> 6);
    if (wid >= NSV) return;
    int rs = rs_h[wid], c = cnt_h[wid];
    float aw = 0.f, au = 0.f;
    int j = 0;
    for (; j + 8 <= c; j += 8) {
      int2 p0 = eh[rs + j],     p1 = eh[rs + j + 1], p2 = eh[rs + j + 2], p3 = eh[rs + j + 3];
      int2 p4 = eh[rs + j + 4], p5 = eh[rs + j + 5], p6 = eh[rs + j + 6], p7 = eh[rs + j + 7];
      float v0 = bf2f(X16[p0.x * 64 + lane]);
      float v1 = bf2f(X16[p1.x * 64 + lane]);
      float v2 = bf2f(X16[p2.x * 64 + lane]);
      float v3 = bf2f(X16[p3.x * 64 + lane]);
      float v4 = bf2f(X16[p4.x * 64 + lane]);
      float v5 = bf2f(X16[p5.x * 64 + lane]);
      float v6 = bf2f(X16[p6.x * 64 + lane]);
      float v7 = bf2f(X16[p7.x * 64 + lane]);
      au += ((v0 + v1) + (v2 + v3)) + ((v4 + v5) + (v6 + v7));
      aw += __int_as_float(p0.y) * v0 + __int_as_float(p1.y) * v1
          + __int_as_float(p2.y) * v2 + __int_as_float(p3.y) * v3
          + __int_as_float(p4.y) * v4 + __int_as_float(p5.y) * v5
          + __int_as_float(p6.y) * v6 + __int_as_float(p7.y) * v7;
    }
    for (; j < c; j++) {
      int2 p = eh[rs + j];
      float v = bf2f(X16[p.x * 64 + lane]);
      au += v; aw += __int_as_float(p.y) * v;
    }
    outw[wid * 64 + lane] = aw;
    outu[wid * 64 + lane] = au;
  } else {
    int wid = (bb - nb64) * 4 + (threadIdx.x >> 6);
    if (wid >= NSV) return;
    int rs = rs_in[wid], c = cnt_in[wid];
    float a = 0.f;
    int j = 0;
    for (; j + 8 <= c; j += 8) {
      int s0 = srcs_in[rs + j],     s1 = srcs_in[rs + j + 1], s2 = srcs_in[rs + j + 2], s3 = srcs_in[rs + j + 3];
      int s4 = srcs_in[rs + j + 4], s5 = srcs_in[rs + j + 5], s6 = srcs_in[rs + j + 6], s7 = srcs_in[rs + j + 7];
      float v0 = bf2f(X16[s0 * 64 + lane]);
      float v1 = bf2f(X16[s1 * 64 + lane]);
      float v2 = bf2f(X16[s2 * 64 + lane]);
      float v3 = bf2f(X16[s3 * 64 + lane]);
      float v4 = bf2f(X16[s4 * 64 + lane]);
      float v5 = bf2f(X16[s5 * 64 + lane]);
      float v6 = bf2f(X16[s6 * 64 + lane]);
      float v7 = bf2f(X16[s7 * 64 + lane]);
      a += ((v0 + v1) + (v2 + v3)) + ((v4 + v5) + (v6 + v7));
    }
    for (; j < c; j++) a += bf2f(X16[srcs_in[rs + j] * 64 + lane]);
    outIN[wid * 64 + lane] = a;
  }
}

__global__ __launch_bounds__(256)
void k_agg64b(const unsigned short* __restrict__ X16,
              const int* __restrict__ rowstart, const int* __restrict__ cnt,
              const int* __restrict__ srcs, float* __restrict__ out, int n) {
  int wid = blockIdx.x * 4 + (threadIdx.x >> 6);
  if (wid >= n) return;
  int lane = threadIdx.x & 63;
  int rs = rowstart[wid], c = cnt[wid];
  float a = 0.f;
  int j = 0;
  for (; j + 8 <= c; j += 8) {
    int s0 = srcs[rs + j],     s1 = srcs[rs + j + 1], s2 = srcs[rs + j + 2], s3 = srcs[rs + j + 3];
    int s4 = srcs[rs + j + 4], s5 = srcs[rs + j + 5], s6 = srcs[rs + j + 6], s7 = srcs[rs + j + 7];
    float v0 = bf2f(X16[s0 * 64 + lane]);
    float v1 = bf2f(X16[s1 * 64 + lane]);
    float v2 = bf2f(X16[s2 * 64 + lane]);
    float v3 = bf2f(X16[s3 * 64 + lane]);
    float v4 = bf2f(X16[s4 * 64 + lane]);
    float v5 = bf2f(X16[s5 * 64 + lane]);
    float v6 = bf2f(X16[s6 * 64 + lane]);
    float v7 = bf2f(X16[s7 * 64 + lane]);
    a += ((v0 + v1) + (v2 + v3)) + ((v4 + v5) + (v6 + v7));
  }
  for (; j < c; j++) a += bf2f(X16[srcs[rs + j] * 64 + lane]);
  out[wid * 64 + lane] = a;
}

// prescaled TAG hop: U = dinv ⊙ t (bf16). t_out = dinv[d]*Σ U[s]; u_out = dinv[d]*t_out.
__global__ __launch_bounds__(256)
void k_tag64b(const unsigned short* __restrict__ U16,
              const int* __restrict__ rowstart, const int* __restrict__ cnt,
              const int* __restrict__ srcs, const float* __restrict__ dinv,
              unsigned short* __restrict__ t_out, unsigned short* __restrict__ u_out, int n) {
  int wid = blockIdx.x * 4 + (threadIdx.x >> 6);
  if (wid >= n) return;
  int lane = threadIdx.x & 63;
  int rs = rowstart[wid], c = cnt[wid];
  float a = 0.f;
  int j = 0;
  for (; j + 8 <= c; j += 8) {
    int s0 = srcs[rs + j],     s1 = srcs[rs + j + 1], s2 = srcs[rs + j + 2], s3 = srcs[rs + j + 3];
    int s4 = srcs[rs + j + 4], s5 = srcs[rs + j + 5], s6 = srcs[rs + j + 6], s7 = srcs[rs + j + 7];
    float v0 = bf2f(U16[s0 * 64 + lane]);
    float v1 = bf2f(U16[s1 * 64 + lane]);
    float v2 = bf2f(U16[s2 * 64 + lane]);
    float v3 = bf2f(U16[s3 * 64 + lane]);
    float v4 = bf2f(U16[s4 * 64 + lane]);
    float v5 = bf2f(U16[s5 * 64 + lane]);
    float v6 = bf2f(U16[s6 * 64 + lane]);
    float v7 = bf2f(U16[s7 * 64 + lane]);
    a += ((v0 + v1) + (v2 + v3)) + ((v4 + v5) + (v6 + v7));
  }
  for (; j < c; j++) a += bf2f(U16[srcs[rs + j] * 64 + lane]);
  float dv = dinv[wid];
  float t = dv * a;
  t_out[wid * 64 + lane] = f2bf(t);
  if (u_out) u_out[wid * 64 + lane] = f2bf(dv * t);
}

// ====================== Fused MM building blocks (512 threads, 2 nodes x 4 feats) ======================

__device__ __forceinline__ void mm_zero2(float acc[2][4]) {
#pragma unroll
  for (int j = 0; j < 2; j++)
#pragma unroll
    for (int jj = 0; jj < 4; jj++) acc[j][jj] = 0.f;
}

__device__ __forceinline__ void mm_acc2(const float* sA, const float* sW, int K,
                                        int nl0, int f0, float acc[2][4]) {
  for (int k = 0; k < K; k++) {
    float4 w = *(const float4*)(&sW[k * 64 + f0]);
#pragma unroll
    for (int j = 0; j < 2; j++) {
      float a = sA[(nl0 + j) * 68 + k];
      acc[j][0] += a * w.x; acc[j][1] += a * w.y; acc[j][2] += a * w.z; acc[j][3] += a * w.w;
    }
  }
}

__device__ __forceinline__ void mm_loadw512(float* Ws, const float* W, int tid) {
  const float4* w4 = (const float4*)W;
  float4* s4 = (float4*)Ws;
  for (int i = tid; i < 1024; i += 512) s4[i] = w4[i];
}

__device__ __forceinline__ void mm_stage_f32_512(float* as, const float* A, const int* cntA,
                                                 int gb, int n, int tid) {
  for (int i = tid; i < 1024; i += 512) {
    int nl = i >> 4, k4 = i & 15;
    int g = gb + nl;
    float4 v = make_float4(0.f, 0.f, 0.f, 0.f);
    if (g < n) {
      v = ((const float4*)A)[g * 16 + k4];
      if (cntA) {
        float sc = 1.0f / fmaxf((float)cntA[g], 1.0f);
        v.x *= sc; v.y *= sc; v.z *= sc; v.w *= sc;
      }
    }
    *(float4*)(&as[nl * 68 + k4 * 4]) = v;
  }
}

__device__ __forceinline__ void mm_stage_bf16_512(float* as, const unsigned short* A,
                                                  int gb, int n, int tid) {
  for (int i = tid; i < 1024; i += 512) {
    int nl = i >> 4, k4 = i & 15;
    int g = gb + nl;
    float4 v = make_float4(0.f, 0.f, 0.f, 0.f);
    if (g < n) {
      uint2 u = ((const uint2*)(A + (size_t)g * 64))[k4];
      v.x = bf2f((unsigned short)(u.x & 0xFFFF));
      v.y = bf2f((unsigned short)(u.x >> 16));
      v.z = bf2f((unsigned short)(u.y & 0xFFFF));
      v.w = bf2f((unsigned short)(u.y >> 16));
    }
    *(float4*)(&as[nl * 68 + k4 * 4]) = v;
  }
}

// ---- phase-C chain (512 threads): S2 = relu(...chain of 4 MMs...) ----
__global__ __launch_bounds__(512, 6)
void k_mm_chainC(const float* __restrict__ aggHw, const float* __restrict__ state_x,
                 const float* __restrict__ aggHu, const int* __restrict__ cnt_h,
                 const float* __restrict__ aggIN, const int* __restrict__ cnt_in,
                 const float* __restrict__ W3_rel, const float* __restrict__ W3_root,
                 const float* __restrict__ b3,
                 const float* __restrict__ W32_l, const float* __restrict__ W32_r,
                 const float* __restrict__ b32,
                 const float* __restrict__ W4_l, const float* __restrict__ W4_r,
                 const float* __restrict__ b4,
                 const float* __restrict__ W42_l, const float* __restrict__ W42_r,
                 const float* __restrict__ b42,
                 float* __restrict__ S2out, unsigned short* __restrict__ S2b,
                 const float* __restrict__ dinvS, int n) {
  __shared__ float Ws[4096];
  __shared__ float as[64 * 68];
  __shared__ float cs[64 * 68];
  const int tid = threadIdx.x;
  const int gb = blockIdx.x * 64;
  const int f0 = (tid & 15) * 4;
  const int nl0 = (tid >> 4) * 2;
  float acc[2][4];

  // --- C1: aggHw@W3_rel + state_x@W3_root + b3, relu -> cs ---
  mm_loadw512(Ws, W3_rel, tid);
  mm_stage_f32_512(as, aggHw, nullptr, gb, n, tid);
  __syncthreads();
  mm_zero2(acc);
  mm_acc2(as, Ws, 64, nl0, f0, acc);
  __syncthreads();
  for (int i = tid; i < 320; i += 512) {
    int nl = i / 5, k = i - nl * 5;
    int g = gb + nl;
    as[nl * 68 + k] = (g < n) ? state_x[(size_t)g * 5 + k] : 0.f;
  }
  for (int i = tid; i < 320; i += 512) Ws[i] = W3_root[i];
  __syncthreads();
  mm_acc2(as, Ws, 5, nl0, f0, acc);
#pragma unroll
  for (int j = 0; j < 2; j++)
#pragma unroll
    for (int jj = 0; jj < 4; jj++)
      cs[(nl0 + j) * 68 + f0 + jj] = fmaxf(acc[j][jj] + b3[f0 + jj], 0.f);
  __syncthreads();

  // --- C2: aggHu'@W32_l + cs@W32_r + b32, relu -> cs ---
  mm_loadw512(Ws, W32_l, tid);
  mm_stage_f32_512(as, aggHu, cnt_h, gb, n, tid);
  __syncthreads();
  mm_zero2(acc);
  mm_acc2(as, Ws, 64, nl0, f0, acc);
  __syncthreads();
  mm_loadw512(Ws, W32_r, tid);
  __syncthreads();
  mm_acc2(cs, Ws, 64, nl0, f0, acc);
  __syncthreads();
#pragma unroll
  for (int j = 0; j < 2; j++)
#pragma unroll
    for (int jj = 0; jj < 4; jj++)
      cs[(nl0 + j) * 68 + f0 + jj] = fmaxf(acc[j][jj] + b32[f0 + jj], 0.f);
  __syncthreads();

  // --- C3: aggIN'@W4_l + cs@W4_r + b4, relu -> cs ---
  mm_loadw512(Ws, W4_l, tid);
  mm_stage_f32_512(as, aggIN, cnt_in, gb, n, tid);
  __syncthreads();
  mm_zero2(acc);
  mm_acc2(as, Ws, 64, nl0, f0, acc);
  __syncthreads();
  mm_loadw512(Ws, W4_r, tid);
  __syncthreads();
  mm_acc2(cs, Ws, 64, nl0, f0, acc);
  __syncthreads();
#pragma unroll
  for (int j = 0; j < 2; j++)
#pragma unroll
    for (int jj = 0; jj < 4; jj++)
      cs[(nl0 + j) * 68 + f0 + jj] = fmaxf(acc[j][jj] + b4[f0 + jj], 0.f);
  __syncthreads();

  // --- C4: aggIN'@W42_l + cs@W42_r + b42, relu -> S2 + S2b(dinv-scaled) ---
  mm_loadw512(Ws, W42_l, tid);
  mm_stage_f32_512(as, aggIN, cnt_in, gb, n, tid);
  __syncthreads();
  mm_zero2(acc);
  mm_acc2(as, Ws, 64, nl0, f0, acc);
  __syncthreads();
  mm_loadw512(Ws, W42_r, tid);
  __syncthreads();
  mm_acc2(cs, Ws, 64, nl0, f0, acc);
#pragma unroll
  for (int j = 0; j < 2; j++) {
    int g = gb + nl0 + j;
    if (g < n) {
      float osc = dinvS[g];
#pragma unroll
      for (int jj = 0; jj < 4; jj++) {
        int f = f0 + jj;
        float v = fmaxf(acc[j][jj] + b42[f], 0.f);
        S2out[(size_t)g * 64 + f] = v;
        S2b[(size_t)g * 64 + f] = f2bf(v * osc);
      }
    }
  }
}

// ---- phase-D quad MM (512 threads) ----
__global__ __launch_bounds__(512, 8)
void k_mm_d(const float* __restrict__ S2, const unsigned short* __restrict__ t1b,
            const unsigned short* __restrict__ t2b, const unsigned short* __restrict__ t3b,
            const float* __restrict__ W2, const float* __restrict__ b2,
            float* __restrict__ S1, unsigned short* __restrict__ S1b, int n) {
  __shared__ float Ws[4096];
  __shared__ float as[64 * 68];
  const int tid = threadIdx.x;
  const int gb = blockIdx.x * 64;
  const int f0 = (tid & 15) * 4;
  const int nl0 = (tid >> 4) * 2;
  float acc[2][4];
  mm_zero2(acc);
  mm_loadw512(Ws, W2, tid);
  mm_stage_f32_512(as, S2, nullptr, gb, n, tid);
  __syncthreads();
  mm_acc2(as, Ws, 64, nl0, f0, acc);
  __syncthreads();
  mm_loadw512(Ws, W2 + 4096, tid);
  mm_stage_bf16_512(as, t1b, gb, n, tid);
  __syncthreads();
  mm_acc2(as, Ws, 64, nl0, f0, acc);
  __syncthreads();
  mm_loadw512(Ws, W2 + 8192, tid);
  mm_stage_bf16_512(as, t2b, gb, n, tid);
  __syncthreads();
  mm_acc2(as, Ws, 64, nl0, f0, acc);
  __syncthreads();
  mm_loadw512(Ws, W2 + 12288, tid);
  mm_stage_bf16_512(as, t3b, gb, n, tid);
  __syncthreads();
  mm_acc2(as, Ws, 64, nl0, f0, acc);
#pragma unroll
  for (int j = 0; j < 2; j++) {
    int g = gb + nl0 + j;
    if (g < n) {
#pragma unroll
      for (int jj = 0; jj < 4; jj++) {
        int f = f0 + jj;
        float v = fmaxf(acc[j][jj] + b2[f], 0.f);
        S1[(size_t)g * 64 + f] = v;
        S1b[(size_t)g * 64 + f] = f2bf(v);
      }
    }
  }
}

// ---- phase-E MM + final projection (512 threads) ----
__global__ __launch_bounds__(512, 6)
void k_mm_e(const float* __restrict__ aggSS, const int* __restrict__ cnt_ss,
            const float* __restrict__ W5_l, const float* __restrict__ S1,
            const float* __restrict__ W5_r, const float* __restrict__ b5,
            const float* __restrict__ Wl, const float* __restrict__ bl,
            float* __restrict__ out, int n) {
  __shared__ float Ws[4096];
  __shared__ float as[64 * 68];
  __shared__ float cs[64 * 68];
  const int tid = threadIdx.x;
  const int gb = blockIdx.x * 64;
  const int f0 = (tid & 15) * 4;
  const int nl0 = (tid >> 4) * 2;
  float acc[2][4];
  mm_zero2(acc);
  mm_loadw512(Ws, W5_l, tid);
  mm_stage_f32_512(as, aggSS, cnt_ss, gb, n, tid);
  __syncthreads();
  mm_acc2(as, Ws, 64, nl0, f0, acc);
  __syncthreads();
  mm_loadw512(Ws, W5_r, tid);
  mm_stage_f32_512(cs, S1, nullptr, gb, n, tid);
  __syncthreads();
  mm_acc2(cs, Ws, 64, nl0, f0, acc);
  __syncthreads();
#pragma unroll
  for (int j = 0; j < 2; j++)
#pragma unroll
    for (int jj = 0; jj < 4; jj++)
      as[(nl0 + j) * 68 + f0 + jj] = fmaxf(acc[j][jj] + b5[f0 + jj], 0.f);
  for (int i = tid; i < 512; i += 512) Ws[i] = Wl[i];
  __syncthreads();
  {
    int nl = tid >> 3, o = tid & 7;
    int g = gb + nl;
    if (g < n) {
      float a2 = bl[o];
#pragma unroll 8
      for (int k = 0; k < 64; k++) a2 += as[nl * 68 + k] * Ws[k * 8 + o];
      out[(size_t)g * 8 + o] = a2;
    }
  }
}

// ---------------- Host ----------------

extern "C" void kernel_launch(void* const* d_in, const int* in_sizes, int n_in,
                              void* d_out, int out_size, void* d_ws, size_t ws_size,
                              hipStream_t stream) {
  const float* game_x  = (const float*)d_in[0];
  const float* state_x = (const float*)d_in[1];
  const int*   ei_vv   = (const int*)d_in[2];
  const int*   et_vv   = (const int*)d_in[3];
  const int*   ei_h    = (const int*)d_in[4];
  const float* ew_h    = (const float*)d_in[5];
  const int*   ei_in   = (const int*)d_in[6];
  const int*   ei_ss   = (const int*)d_in[7];
  const float* W1_rel  = (const float*)d_in[8];
  const float* W1_root = (const float*)d_in[9];
  const float* b1      = (const float*)d_in[10];
  const float* W12     = (const float*)d_in[11];
  const float* b12     = (const float*)d_in[12];
  const float* W2      = (const float*)d_in[13];
  const float* b2      = (const float*)d_in[14];
  const float* W3_rel  = (const float*)d_in[15];
  const float* W3_root = (const float*)d_in[16];
  const float* b3      = (const float*)d_in[17];
  const float* W32_l   = (const float*)d_in[18];
  const float* W32_r   = (const float*)d_in[19];
  const float* b32     = (const float*)d_in[20];
  const float* W4_l    = (const float*)d_in[21];
  const float* W4_r    = (const float*)d_in[22];
  const float* b4      = (const float*)d_in[23];
  const float* W42_l   = (const float*)d_in[24];
  const float* W42_r   = (const float*)d_in[25];
  const float* b42     = (const float*)d_in[26];
  const float* W5_l    = (const float*)d_in[27];
  const float* W5_r    = (const float*)d_in[28];
  const float* b5      = (const float*)d_in[29];
  const float* Wl      = (const float*)d_in[30];
  const float* bl      = (const float*)d_in[31];

  // Workspace (4B slots), peak 26.05M slots = 104.2 MiB.
  float* ws = (float*)d_ws;
  int*   cnt_all = (int*)(ws + 0);              // 250K (vv|h|in|ss)
  int*   rs_all  = (int*)(ws + 250000);         // 250K (graph-local values)
  int*   bcnt    = (int*)(ws + 500000);         // 512
  int*   bbase   = (int*)(ws + 500512);         // 512
  int*   cb      = (int*)(ws + 501024);         // 512
  int*   srcs_ss = (int*)(ws + 760000);         // 0.8M  (lives through phase E)
  float4* x_pad  = (float4*)(ws + 1600000);     // 800K
  float4* h1p    = (float4*)(ws + 2400000);
  float4* h2p    = (float4*)(ws + 3200000);
  float4* h3p    = (float4*)(ws + 4000000);
  float4* ra4all = (float4*)(ws + 4800000);     // [NVV][5] float4 = 2.0M slots -> 6.8M
  float* dinvS   = ws + 6800000;                // 50K
  unsigned short* gx16 = (unsigned short*)(ws + 6850000);  // 3.2M slots -> 10.05M
  unsigned* temp_vv    = (unsigned*)(ws + 6850000);        // 1.6M, overlays gx16 front (dead before combine)
  float* aggHw = ws + 10050000;                 // 3.2M
  float* aggHu = ws + 13250000;                 // 3.2M
  float* aggIN = ws + 16450000;                 // 3.2M
  float* S1    = ws + 19650000;                 // 3.2M
  float* S2    = ws + 22850000;                 // 3.2M -> ends 26.05M
  // fill temps overlay agg regions (dead until phase B):
  uint2*    temp_h  = (uint2*)aggHw;
  unsigned* temp_in = (unsigned*)(aggHw + 1600000);
  unsigned* temp_ss = (unsigned*)(aggHw + 2400000);
  // overlays (dead-before-write verified in stream order):
  unsigned short* S2b = (unsigned short*)(ws + 4800000);     // in ra4all region (dead after combine_gx)
  unsigned short* u1b = (unsigned short*)(aggHw + 1600000);  // hop1 aux; aggHw dead after chainC
  float*          aggSS = aggHw + 1600000;                   // phase E (after u1b dead)
  unsigned short* t1b = (unsigned short*)aggHu;              // aggHu dead after chainC
  unsigned short* t2b = (unsigned short*)(aggHu + 1600000);
  unsigned short* t3b = (unsigned short*)aggIN;              // aggIN dead after chainC
  unsigned short* S1b = (unsigned short*)(aggIN + 1600000);  // k_mm_d shadow
  unsigned* payload_vv = (unsigned*)S1;                      // dead after phase A
  unsigned short* u2b  = (unsigned short*)S1;                // hop2 aux; S1 written later by k_mm_d
  int2*     eh         = (int2*)S2;                          // dead after aggB; S2 written by chainC
  int*      srcs_in    = (int*)(S2 + 1600000);

  const int* src_vv = ei_vv;  const int* dst_vv = ei_vv + E_VV;
  const int* src_h  = ei_h;   const int* dst_h  = ei_h + E_H;
  const int* src_in = ei_in;  const int* dst_in = ei_in + E_IN;
  const int* src_ss = ei_ss;  const int* dst_ss = ei_ss + E_SS;

  auto nblk = [](long long n) { return dim3((unsigned)((n + 255) / 256)); };
  const int NB64 = (NSV + 3) / 4;
  const int NB   = (NSV + 63) / 64;
  const int GC   = (ETOT + TC - 1) / TC;

  int* cnt_h  = cnt_all + H_ROW;
  int* cnt_in = cnt_all + IN_ROW;
  int* cnt_ss = cnt_all + SS_ROW;
  int* rs_vv  = rs_all;
  int* rs_h   = rs_all + H_ROW;
  int* rs_in  = rs_all + IN_ROW;
  int* rs_ss  = rs_all + SS_ROW;

  // ---- CSR build (fused) ----
  hipMemsetAsync(bcnt, 0, NBTOT * sizeof(int), stream);
  k_bucket_count<<<GC, 256, 0, stream>>>(dst_vv, dst_h, dst_in, dst_ss, bcnt);
  k_bucket_scan<<<1, 512, 0, stream>>>(bcnt, bbase, cb);
  k_fill_s1_all<<<SB1, 256, 0, stream>>>(src_vv, dst_vv, et_vv, src_h, dst_h, ew_h,
                                         src_in, dst_in, src_ss, dst_ss, cb,
                                         temp_vv, temp_h, temp_in, temp_ss);
  k_fill_s2_all<<<NBTOT, 256, 0, stream>>>(temp_vv, temp_h, temp_in, temp_ss, bbase,
                                           payload_vv, eh, srcs_in, srcs_ss,
                                           rs_all, cnt_all, game_x, x_pad, dinvS);

  // ---- Phase A: v-graph 5-dim ----
  k_vv_pass1<<<nblk(NVV), 256, 0, stream>>>(x_pad, rs_vv, cnt_all, payload_vv, ra4all, h1p);
  k_vv_hop<<<nblk(NVV), 256, 0, stream>>>(h1p, rs_vv, cnt_all, payload_vv, h2p);
  k_vv_hop<<<nblk(NVV), 256, 0, stream>>>(h2p, rs_vv, cnt_all, payload_vv, h3p);
  k_combine_gx<<<dim3((NVV + 31) / 32), 256, 0, stream>>>(x_pad, ra4all, h1p, h2p, h3p,
                                                          W1_rel, W1_root, b1, W12, b12, gx16);

  // ---- Phase B: fused 64-dim bf16 gathers ----
  k_aggB<<<2 * NB64, 256, 0, stream>>>(gx16, rs_h, cnt_h, eh, rs_in, cnt_in, srcs_in,
                                       aggHw, aggHu, aggIN, NB64);

  // ---- Phase C: fused 4-MM chain (512 threads) -> S2 (+ dinv-prescaled bf16 shadow) ----
  k_mm_chainC<<<NB, 512, 0, stream>>>(aggHw, state_x, aggHu, cnt_h, aggIN, cnt_in,
                                      W3_rel, W3_root, b3, W32_l, W32_r, b32,
                                      W4_l, W4_r, b4, W42_l, W42_r, b42,
                                      S2, S2b, dinvS, NSV);

  // ---- Phase D: TAG on s-s (prescaled bf16 hops) + fused quad MM ----
  k_tag64b<<<NB64, 256, 0, stream>>>(S2b, rs_ss, cnt_ss, srcs_ss, dinvS, t1b, u1b, NSV);
  k_tag64b<<<NB64, 256, 0, stream>>>(u1b, rs_ss, cnt_ss, srcs_ss, dinvS, t2b, u2b, NSV);
  k_tag64b<<<NB64, 256, 0, stream>>>(u2b, rs_ss, cnt_ss, srcs_ss, dinvS, t3b, nullptr, NSV);
  k_mm_d<<<NB, 512, 0, stream>>>(S2, t1b, t2b, t3b, W2, b2, S1, S1b, NSV);

  // ---- Phase E: SAGE on s-s + final projection ----
  k_agg64b<<<NB64, 256, 0, stream>>>(S1b, rs_ss, cnt_ss, srcs_ss, aggSS, NSV);
  k_mm_e<<<NB, 512, 0, stream>>>(aggSS, cnt_ss, W5_l, S1, W5_r, b5, Wl, bl, (float*)d_out, NSV);
}

// Round 13
// 3786.865 us; speedup vs baseline: 1.0074x; 1.0074x over previous
//
#include <hip/hip_runtime.h>

#define NVV 100000
#define NSV 50000
#define E_VV 1600000
#define E_H  800000
#define E_IN 800000
#define E_SS 800000
#define ETOT 4000000
#define DIN 5
#define H_ROW 100000          // concatenated cnt/rs space: vv|h|in|ss
#define IN_ROW 150000
#define SS_ROW 200000
#define NROWS 250000
#define POS_H  E_VV
#define POS_IN (E_VV + E_H)
#define POS_SS (E_VV + E_H + E_IN)
#define NBUK 196              // vv buckets (dst >> 9)
#define NBUKS 98              // NSV-graph buckets
#define NBTOT 490             // vv|h|in|ss bucket space
#define BUK_H  196
#define BUK_IN 294
#define BUK_SS 392
#define BSHIFT 9
#define T1 4096               // edges per fill-stage-1 block
#define TC 16384              // edges per bucket-count block
#define G1VV 391              // ceil(E_VV/T1)
#define G1S  196              // ceil(E_H/T1)
#define SB1  (G1VV + 3 * G1S) // 979 fused stage-1 blocks

__device__ __forceinline__ unsigned short f2bf(float x) {
  unsigned b = __float_as_uint(x);
  return (unsigned short)((b + 0x7FFFu + ((b >> 16) & 1u)) >> 16);
}
__device__ __forceinline__ float bf2f(unsigned short u) {
  return __uint_as_float(((unsigned)u) << 16);
}

// ====================== CSR build: bucket counts -> bases -> fused binned fills ======================

__global__ __launch_bounds__(256)
void k_bucket_count(const int* __restrict__ d_vv, const int* __restrict__ d_h,
                    const int* __restrict__ d_in, const int* __restrict__ d_ss,
                    int* __restrict__ bcnt) {
  __shared__ int h[NBTOT];
  const int tid = threadIdx.x;
  for (int i = tid; i < NBTOT; i += 256) h[i] = 0;
  __syncthreads();
  const int base = blockIdx.x * TC;
#pragma unroll 4
  for (int k = 0; k < TC / 256; k++) {
    int e = base + k * 256 + tid;
    int bi = -1;
    if (e < E_VV) bi = d_vv[e] >> BSHIFT;
    else if (e < POS_IN) bi = BUK_H + (d_h[e - POS_H] >> BSHIFT);
    else if (e < POS_SS) bi = BUK_IN + (d_in[e - POS_IN] >> BSHIFT);
    else if (e < ETOT) bi = BUK_SS + (d_ss[e - POS_SS] >> BSHIFT);
    if (bi >= 0) atomicAdd(&h[bi], 1);
  }
  __syncthreads();
  for (int i = tid; i < NBTOT; i += 256) if (h[i]) atomicAdd(&bcnt[i], h[i]);
}

__global__ __launch_bounds__(512)
void k_bucket_scan(const int* __restrict__ bcnt, int* __restrict__ bbase, int* __restrict__ cb) {
  __shared__ int sd[512];
  int t = threadIdx.x;
  int v = (t < NBTOT) ? bcnt[t] : 0;
  sd[t] = v; __syncthreads();
  for (int off = 1; off < 512; off <<= 1) {
    int x = (t >= off) ? sd[t - off] : 0;
    __syncthreads();
    sd[t] += x;
    __syncthreads();
  }
  int segstart = (t < BUK_H) ? 0 : (t < BUK_IN) ? BUK_H : (t < BUK_SS) ? BUK_IN : BUK_SS;
  int excl = ((t > 0) ? sd[t - 1] : 0) - ((segstart > 0) ? sd[segstart - 1] : 0);
  if (t < NBTOT) { bbase[t] = excl; cb[t] = excl; }
}

// ---- fused stage 1: all 4 graphs, bucket-grouped binning, coalesced run writes ----
__global__ __launch_bounds__(256)
void k_fill_s1_all(const int* __restrict__ s_vv, const int* __restrict__ d_vv,
                   const int* __restrict__ et,
                   const int* __restrict__ s_h, const int* __restrict__ d_h,
                   const float* __restrict__ ew,
                   const int* __restrict__ s_in, const int* __restrict__ d_in,
                   const int* __restrict__ s_ss, const int* __restrict__ d_ss,
                   int* __restrict__ cb,
                   unsigned* __restrict__ temp_vv, uint2* __restrict__ temp_h,
                   unsigned* __restrict__ temp_in, unsigned* __restrict__ temp_ss) {
  __shared__ int hist[NBUK], lbase[NBUK], run[NBUK], gb[NBUK];
  __shared__ int sc[256];
  __shared__ unsigned stage[T1];
  __shared__ unsigned stageW[T1];
  __shared__ int gpos[T1];
  const int tid = threadIdx.x;
  const int b = blockIdx.x;
  int g, tile;
  if (b < G1VV) { g = 0; tile = b; }
  else if (b < G1VV + G1S) { g = 1; tile = b - G1VV; }
  else if (b < G1VV + 2 * G1S) { g = 2; tile = b - G1VV - G1S; }
  else { g = 3; tile = b - G1VV - 2 * G1S; }
  const int ne = (g == 0) ? E_VV : E_H;
  const int nbuk = (g == 0) ? NBUK : NBUKS;
  const int cboff = (g == 0) ? 0 : (g == 1) ? BUK_H : (g == 2) ? BUK_IN : BUK_SS;
  const int* S = (g == 0) ? s_vv : (g == 1) ? s_h : (g == 2) ? s_in : s_ss;
  const int* D = (g == 0) ? d_vv : (g == 1) ? d_h : (g == 2) ? d_in : d_ss;
  const int base = tile * T1;
  const int nvalid = min(T1, ne - base);
  for (int i = tid; i < nbuk; i += 256) { hist[i] = 0; run[i] = 0; }
  __syncthreads();
  int dv[16]; unsigned pk[16], pkw[16];
#pragma unroll
  for (int k = 0; k < 16; k++) {
    int e = base + k * 256 + tid;
    if (e - base < nvalid) {
      int d = D[e];
      dv[k] = d;
      if (g == 0) pk[k] = (unsigned)(((d & 511) << 19) | (et[e] << 17) | S[e]);
      else pk[k] = (unsigned)(((d & 511) << 17) | S[e]);
      if (g == 1) pkw[k] = (unsigned)__float_as_int(ew[e]);
      atomicAdd(&hist[d >> BSHIFT], 1);
    } else dv[k] = -1;
  }
  __syncthreads();
  int my = (tid < nbuk) ? hist[tid] : 0;
  sc[tid] = my; __syncthreads();
  for (int off = 1; off < 256; off <<= 1) {
    int t = (tid >= off) ? sc[tid - off] : 0;
    __syncthreads();
    sc[tid] += t;
    __syncthreads();
  }
  if (tid < nbuk) {
    lbase[tid] = sc[tid] - my;
    gb[tid] = my ? atomicAdd(&cb[cboff + tid], my) : 0;
  }
  __syncthreads();
#pragma unroll
  for (int k = 0; k < 16; k++) {
    if (dv[k] >= 0) {
      int bu = dv[k] >> BSHIFT;
      int loc = atomicAdd(&run[bu], 1);
      int li = lbase[bu] + loc;
      stage[li] = pk[k];
      if (g == 1) stageW[li] = pkw[k];
      gpos[li] = gb[bu] + loc;
    }
  }
  __syncthreads();
  if (g == 0)      for (int i = tid; i < nvalid; i += 256) temp_vv[gpos[i]] = stage[i];
  else if (g == 1) for (int i = tid; i < nvalid; i += 256) temp_h[gpos[i]] = make_uint2(stage[i], stageW[i]);
  else if (g == 2) for (int i = tid; i < nvalid; i += 256) temp_in[gpos[i]] = stage[i];
  else             for (int i = tid; i < nvalid; i += 256) temp_ss[gpos[i]] = stage[i];
}

// ---- fused stage 2 ----
__global__ __launch_bounds__(256)
void k_fill_s2_all(const unsigned* __restrict__ temp_vv, const uint2* __restrict__ temp_h,
                   const unsigned* __restrict__ temp_in, const unsigned* __restrict__ temp_ss,
                   const int* __restrict__ bbase,
                   unsigned* __restrict__ payload_vv, int2* __restrict__ eh,
                   int* __restrict__ srcs_in, int* __restrict__ srcs_ss,
                   int* __restrict__ rs_all, int* __restrict__ cnt_all,
                   const float* __restrict__ x, float4* __restrict__ xp,
                   float* __restrict__ dinvS) {
  __shared__ int lcnt[512], lpos[512];
  __shared__ int sc[256];
  const int b = blockIdx.x, tid = threadIdx.x;
  int g, lb;
  if (b < BUK_H) { g = 0; lb = b; }
  else if (b < BUK_IN) { g = 1; lb = b - BUK_H; }
  else if (b < BUK_SS) { g = 2; lb = b - BUK_IN; }
  else { g = 3; lb = b - BUK_SS; }
  const int d0 = lb << BSHIFT;
  const int nrows = (g == 0) ? NVV : NSV;
  const int rowbase = (g == 0) ? 0 : (g == 1) ? H_ROW : (g == 2) ? IN_ROW : SS_ROW;
  const int ne = (g == 0) ? E_VV : E_H;
  const int lastb = (g == 0) ? NBUK - 1 : NBUKS - 1;
  const int shift = (g == 0) ? 19 : 17;
  lcnt[tid] = 0; lcnt[tid + 256] = 0;
  __syncthreads();
  const int gstart = bbase[b];
  const int gend = (lb == lastb) ? ne : bbase[b + 1];
  if (g == 1) {
    for (int i = gstart + tid; i < gend; i += 256) atomicAdd(&lcnt[temp_h[i].x >> 17], 1);
  } else {
    const unsigned* tp = (g == 0) ? temp_vv : (g == 2) ? temp_in : temp_ss;
    for (int i = gstart + tid; i < gend; i += 256) atomicAdd(&lcnt[tp[i] >> shift], 1);
  }
  __syncthreads();
  int c0 = lcnt[2 * tid], c1 = lcnt[2 * tid + 1];
  int ps = c0 + c1;
  sc[tid] = ps; __syncthreads();
  for (int off = 1; off < 256; off <<= 1) {
    int x2 = (tid >= off) ? sc[tid - off] : 0;
    __syncthreads();
    sc[tid] += x2;
    __syncthreads();
  }
  int basep = gstart + sc[tid] - ps;
  lpos[2 * tid] = basep;
  lpos[2 * tid + 1] = basep + c0;
  __syncthreads();
  for (int d = tid; d < 512; d += 256) {
    int gd = d0 + d;
    if (gd < nrows) {
      rs_all[rowbase + gd] = lpos[d];
      cnt_all[rowbase + gd] = lcnt[d];
      if (g == 0) {
        float dc = (float)lcnt[d];
        float di = dc > 0.f ? rsqrtf(dc) : 0.f;
        const float* xr = x + (size_t)gd * 5;
        xp[gd * 2]     = make_float4(xr[0], xr[1], xr[2], xr[3]);
        xp[gd * 2 + 1] = make_float4(xr[4], di, 0.f, 0.f);
      } else if (g == 3) {
        float dc = (float)lcnt[d];
        dinvS[gd] = dc > 0.f ? rsqrtf(dc) : 0.f;
      }
    }
  }
  __syncthreads();
  if (g == 0) {
    for (int i = gstart + tid; i < gend; i += 256) {
      unsigned en = temp_vv[i];
      int pos = atomicAdd(&lpos[en >> 19], 1);
      payload_vv[pos] = en & 0x7FFFFu;
    }
  } else if (g == 1) {
    for (int i = gstart + tid; i < gend; i += 256) {
      uint2 en = temp_h[i];
      int pos = atomicAdd(&lpos[en.x >> 17], 1);
      eh[pos] = make_int2((int)(en.x & 0x1FFFFu), (int)en.y);
    }
  } else if (g == 2) {
    for (int i = gstart + tid; i < gend; i += 256) {
      unsigned en = temp_in[i];
      int pos = atomicAdd(&lpos[en >> 17], 1);
      srcs_in[pos] = (int)(en & 0x1FFFFu);
    }
  } else {
    for (int i = gstart + tid; i < gend; i += 256) {
      unsigned en = temp_ss[i];
      int pos = atomicAdd(&lpos[en >> 17], 1);
      srcs_ss[pos] = (int)(en & 0x1FFFFu);
    }
  }
}

// ====================== Phase A: v-graph (5-dim, padded rows) ======================

__global__ __launch_bounds__(256)
void k_vv_pass1(const float4* __restrict__ xp,
                const int* __restrict__ rowstart, const int* __restrict__ cnt,
                const unsigned* __restrict__ payload,
                float4* __restrict__ ra4all, float4* __restrict__ h1p) {
  int d = blockIdx.x * 256 + threadIdx.x;
  if (d >= NVV) return;
  int rs = rowstart[d], c = cnt[d];
  float a0[5] = {0,0,0,0,0}, a1[5] = {0,0,0,0,0}, a2[5] = {0,0,0,0,0}, h[5] = {0,0,0,0,0};
  float c0 = 0.f, c1 = 0.f, c2 = 0.f;
  int j = 0;
  for (; j + 2 <= c; j += 2) {
    unsigned pA = payload[rs + j], pB = payload[rs + j + 1];
    int sA = pA & 0x1FFFF, rA = pA >> 17;
    int sB = pB & 0x1FFFF, rB = pB >> 17;
    float4 xA0 = xp[sA * 2], xA1 = xp[sA * 2 + 1];
    float4 xB0 = xp[sB * 2], xB1 = xp[sB * 2 + 1];
    float xsA[5] = {xA0.x, xA0.y, xA0.z, xA0.w, xA1.x};
    float xsB[5] = {xB0.x, xB0.y, xB0.z, xB0.w, xB1.x};
    float wA = xA1.y, wB = xB1.y;
    float mA0 = (rA == 0) ? 1.f : 0.f, mA1 = (rA == 1) ? 1.f : 0.f, mA2 = (rA == 2) ? 1.f : 0.f;
    float mB0 = (rB == 0) ? 1.f : 0.f, mB1 = (rB == 1) ? 1.f : 0.f, mB2 = (rB == 2) ? 1.f : 0.f;
    c0 += mA0 + mB0; c1 += mA1 + mB1; c2 += mA2 + mB2;
#pragma unroll
    for (int k = 0; k < 5; k++) {
      h[k] += wA * xsA[k] + wB * xsB[k];
      a0[k] += mA0 * xsA[k] + mB0 * xsB[k];
      a1[k] += mA1 * xsA[k] + mB1 * xsB[k];
      a2[k] += mA2 * xsA[k] + mB2 * xsB[k];
    }
  }
  for (; j < c; j++) {
    unsigned p = payload[rs + j];
    int s = p & 0x1FFFF, r = p >> 17;
    float4 x0 = xp[s * 2], x1 = xp[s * 2 + 1];
    float xs[5] = {x0.x, x0.y, x0.z, x0.w, x1.x};
    float wsc = x1.y;
    float m0 = (r == 0) ? 1.f : 0.f, m1 = (r == 1) ? 1.f : 0.f, m2 = (r == 2) ? 1.f : 0.f;
    c0 += m0; c1 += m1; c2 += m2;
#pragma unroll
    for (int k = 0; k < 5; k++) {
      h[k] += wsc * xs[k];
      a0[k] += m0 * xs[k]; a1[k] += m1 * xs[k]; a2[k] += m2 * xs[k];
    }
  }
  float dv = xp[d * 2 + 1].y;
  float4* ra4 = ra4all + d * 5;
  ra4[0] = make_float4(a0[0], a0[1], a0[2], a0[3]);
  ra4[1] = make_float4(a0[4], a1[0], a1[1], a1[2]);
  ra4[2] = make_float4(a1[3], a1[4], a2[0], a2[1]);
  ra4[3] = make_float4(a2[2], a2[3], a2[4], c0);
  ra4[4] = make_float4(c1, c2, 0.f, 0.f);
  h1p[d * 2]     = make_float4(dv * h[0], dv * h[1], dv * h[2], dv * h[3]);
  h1p[d * 2 + 1] = make_float4(dv * h[4], dv, 0.f, 0.f);
}

__global__ __launch_bounds__(256)
void k_vv_hop(const float4* __restrict__ hinp,
              const int* __restrict__ rowstart, const int* __restrict__ cnt,
              const unsigned* __restrict__ payload, float4* __restrict__ houtp) {
  int d = blockIdx.x * 256 + threadIdx.x;
  if (d >= NVV) return;
  int rs = rowstart[d], c = cnt[d];
  float h[5] = {0,0,0,0,0};
  int j = 0;
  for (; j + 4 <= c; j += 4) {
    unsigned p0 = payload[rs + j], p1 = payload[rs + j + 1];
    unsigned p2 = payload[rs + j + 2], p3 = payload[rs + j + 3];
    int s0 = p0 & 0x1FFFF, s1 = p1 & 0x1FFFF, s2 = p2 & 0x1FFFF, s3 = p3 & 0x1FFFF;
    float4 a0 = hinp[s0 * 2], b0 = hinp[s0 * 2 + 1];
    float4 a1 = hinp[s1 * 2], b1 = hinp[s1 * 2 + 1];
    float4 a2 = hinp[s2 * 2], b2 = hinp[s2 * 2 + 1];
    float4 a3 = hinp[s3 * 2], b3 = hinp[s3 * 2 + 1];
    float w0 = b0.y, w1 = b1.y, w2 = b2.y, w3 = b3.y;
    h[0] += w0 * a0.x + w1 * a1.x + w2 * a2.x + w3 * a3.x;
    h[1] += w0 * a0.y + w1 * a1.y + w2 * a2.y + w3 * a3.y;
    h[2] += w0 * a0.z + w1 * a1.z + w2 * a2.z + w3 * a3.z;
    h[3] += w0 * a0.w + w1 * a1.w + w2 * a2.w + w3 * a3.w;
    h[4] += w0 * b0.x + w1 * b1.x + w2 * b2.x + w3 * b3.x;
  }
  for (; j < c; j++) {
    int s = payload[rs + j] & 0x1FFFF;
    float4 x0 = hinp[s * 2], x1 = hinp[s * 2 + 1];
    float wsc = x1.y;
    h[0] += wsc * x0.x; h[1] += wsc * x0.y; h[2] += wsc * x0.z; h[3] += wsc * x0.w;
    h[4] += wsc * x1.x;
  }
  float dv = hinp[d * 2 + 1].y;
  houtp[d * 2]     = make_float4(dv * h[0], dv * h[1], dv * h[2], dv * h[3]);
  houtp[d * 2 + 1] = make_float4(dv * h[4], dv, 0.f, 0.f);
}

// 8 nodes/thread, Ws column in 35 VGPRs, float4 relall loads.
__global__ __launch_bounds__(256)
void k_combine_gx(const float4* __restrict__ xp,
                  const float4* __restrict__ ra4all,
                  const float4* __restrict__ h1p, const float4* __restrict__ h2p,
                  const float4* __restrict__ h3p,
                  const float* __restrict__ W1_rel, const float* __restrict__ W1_root,
                  const float* __restrict__ b1,
                  const float* __restrict__ W12, const float* __restrict__ b12,
                  unsigned short* __restrict__ gx16) {
  __shared__ float Ws[7 * 320];
  __shared__ float bs[64];
  int tid = threadIdx.x;
  for (int i = tid; i < 320; i += 256) {
    Ws[i]        = W1_root[i] + W12[i];
    Ws[320 + i]  = W1_rel[i];
    Ws[640 + i]  = W1_rel[320 + i];
    Ws[960 + i]  = W1_rel[640 + i];
    Ws[1280 + i] = W12[320 + i];
    Ws[1600 + i] = W12[640 + i];
    Ws[1920 + i] = W12[960 + i];
  }
  if (tid < 64) bs[tid] = b1[tid] + b12[tid];
  __syncthreads();
  const int f = tid & 63;
  const int grp = tid >> 6;
  float wcol[35];
#pragma unroll
  for (int t = 0; t < 35; t++) wcol[t] = Ws[t * 64 + f];
  const float bias = bs[f];
  const int v0 = blockIdx.x * 32 + grp * 8;
  for (int n = 0; n < 8; n++) {
    int v = v0 + n;
    if (v >= NVV) return;
    float in[35];
    {
      float4 x0 = xp[v * 2], x1 = xp[v * 2 + 1];
      in[0] = x0.x; in[1] = x0.y; in[2] = x0.z; in[3] = x0.w; in[4] = x1.x;
    }
    {
      const float4* ra = ra4all + v * 5;
      float4 r0 = ra[0], r1 = ra[1], r2 = ra[2], r3 = ra[3], r4 = ra[4];
      float i0 = 1.0f / fmaxf(r3.w, 1.0f);
      float i1 = 1.0f / fmaxf(r4.x, 1.0f);
      float i2 = 1.0f / fmaxf(r4.y, 1.0f);
      in[5]  = r0.x * i0; in[6]  = r0.y * i0; in[7]  = r0.z * i0; in[8]  = r0.w * i0; in[9]  = r1.x * i0;
      in[10] = r1.y * i1; in[11] = r1.z * i1; in[12] = r1.w * i1; in[13] = r2.x * i1; in[14] = r2.y * i1;
      in[15] = r2.z * i2; in[16] = r2.w * i2; in[17] = r3.x * i2; in[18] = r3.y * i2; in[19] = r3.z * i2;
    }
    {
      float4 a = h1p[v * 2], b = h1p[v * 2 + 1];
      in[20] = a.x; in[21] = a.y; in[22] = a.z; in[23] = a.w; in[24] = b.x;
      a = h2p[v * 2]; b = h2p[v * 2 + 1];
      in[25] = a.x; in[26] = a.y; in[27] = a.z; in[28] = a.w; in[29] = b.x;
      a = h3p[v * 2]; b = h3p[v * 2 + 1];
      in[30] = a.x; in[31] = a.y; in[32] = a.z; in[33] = a.w; in[34] = b.x;
    }
    float acc = bias;
#pragma unroll
    for (int t = 0; t < 35; t++) acc += in[t] * wcol[t];
    gx16[v * 64 + f] = f2bf(acc);
  }
}

// ================= 64-dim CSR gathers (wave per dst, lane=feature, 8-way MLP) =================

__global__ __launch_bounds__(256)
void k_aggB(const unsigned short* __restrict__ X16,
            const int* __restrict__ rs_h, const int* __restrict__ cnt_h,
            const int2* __restrict__ eh,
            const int* __restrict__ rs_in, const int* __restrict__ cnt_in,
            const int* __restrict__ srcs_in,
            float* __restrict__ outw, float* __restrict__ outu, float* __restrict__ outIN,
            int nb64) {
  int bb = blockIdx.x;
  int lane = threadIdx.x & 63;
  if (bb < nb64) {
    int wid = bb * 4 + (threadIdx.x >> 6);
    if (wid >= NSV) return;
    int rs = rs_h[wid], c = cnt_h[wid];
    float aw = 0.f, au = 0.f;
    int j = 0;
    for (; j + 8 <= c; j += 8) {
      int2 p0 = eh[rs + j],     p1 = eh[rs + j + 1], p2 = eh[rs + j + 2], p3 = eh[rs + j + 3];
      int2 p4 = eh[rs + j + 4], p5 = eh[rs + j + 5], p6 = eh[rs + j + 6], p7 = eh[rs + j + 7];
      float v0 = bf2f(X16[p0.x * 64 + lane]);
      float v1 = bf2f(X16[p1.x * 64 + lane]);
      float v2 = bf2f(X16[p2.x * 64 + lane]);
      float v3 = bf2f(X16[p3.x * 64 + lane]);
      float v4 = bf2f(X16[p4.x * 64 + lane]);
      float v5 = bf2f(X16[p5.x * 64 + lane]);
      float v6 = bf2f(X16[p6.x * 64 + lane]);
      float v7 = bf2f(X16[p7.x * 64 + lane]);
      au += ((v0 + v1) + (v2 + v3)) + ((v4 + v5) + (v6 + v7));
      aw += __int_as_float(p0.y) * v0 + __int_as_float(p1.y) * v1
          + __int_as_float(p2.y) * v2 + __int_as_float(p3.y) * v3
          + __int_as_float(p4.y) * v4 + __int_as_float(p5.y) * v5
          + __int_as_float(p6.y) * v6 + __int_as_float(p7.y) * v7;
    }
    for (; j < c; j++) {
      int2 p = eh[rs + j];
      float v = bf2f(X16[p.x * 64 + lane]);
      au += v; aw += __int_as_float(p.y) * v;
    }
    outw[wid * 64 + lane] = aw;
    outu[wid * 64 + lane] = au;
  } else {
    int wid = (bb - nb64) * 4 + (threadIdx.x >> 6);
    if (wid >= NSV) return;
    int rs = rs_in[wid], c = cnt_in[wid];
    float a = 0.f;
    int j = 0;
    for (; j + 8 <= c; j += 8) {
      int s0 = srcs_in[rs + j],     s1 = srcs_in[rs + j + 1], s2 = srcs_in[rs + j + 2], s3 = srcs_in[rs + j + 3];
      int s4 = srcs_in[rs + j + 4], s5 = srcs_in[rs + j + 5], s6 = srcs_in[rs + j + 6], s7 = srcs_in[rs + j + 7];
      float v0 = bf2f(X16[s0 * 64 + lane]);
      float v1 = bf2f(X16[s1 * 64 + lane]);
      float v2 = bf2f(X16[s2 * 64 + lane]);
      float v3 = bf2f(X16[s3 * 64 + lane]);
      float v4 = bf2f(X16[s4 * 64 + lane]);
      float v5 = bf2f(X16[s5 * 64 + lane]);
      float v6 = bf2f(X16[s6 * 64 + lane]);
      float v7 = bf2f(X16[s7 * 64 + lane]);
      a += ((v0 + v1) + (v2 + v3)) + ((v4 + v5) + (v6 + v7));
    }
    for (; j < c; j++) a += bf2f(X16[srcs_in[rs + j] * 64 + lane]);
    outIN[wid * 64 + lane] = a;
  }
}

__global__ __launch_bounds__(256)
void k_agg64b(const unsigned short* __restrict__ X16,
              const int* __restrict__ rowstart, const int* __restrict__ cnt,
              const int* __restrict__ srcs, float* __restrict__ out, int n) {
  int wid = blockIdx.x * 4 + (threadIdx.x >> 6);
  if (wid >= n) return;
  int lane = threadIdx.x & 63;
  int rs = rowstart[wid], c = cnt[wid];
  float a = 0.f;
  int j = 0;
  for (; j + 8 <= c; j += 8) {
    int s0 = srcs[rs + j],     s1 = srcs[rs + j + 1], s2 = srcs[rs + j + 2], s3 = srcs[rs + j + 3];
    int s4 = srcs[rs + j + 4], s5 = srcs[rs + j + 5], s6 = srcs[rs + j + 6], s7 = srcs[rs + j + 7];
    float v0 = bf2f(X16[s0 * 64 + lane]);
    float v1 = bf2f(X16[s1 * 64 + lane]);
    float v2 = bf2f(X16[s2 * 64 + lane]);
    float v3 = bf2f(X16[s3 * 64 + lane]);
    float v4 = bf2f(X16[s4 * 64 + lane]);
    float v5 = bf2f(X16[s5 * 64 + lane]);
    float v6 = bf2f(X16[s6 * 64 + lane]);
    float v7 = bf2f(X16[s7 * 64 + lane]);
    a += ((v0 + v1) + (v2 + v3)) + ((v4 + v5) + (v6 + v7));
  }
  for (; j < c; j++) a += bf2f(X16[srcs[rs + j] * 64 + lane]);
  out[wid * 64 + lane] = a;
}

// prescaled TAG hop: U = dinv ⊙ t (bf16). t_out = dinv[d]*Σ U[s]; u_out = dinv[d]*t_out.
__global__ __launch_bounds__(256)
void k_tag64b(const unsigned short* __restrict__ U16,
              const int* __restrict__ rowstart, const int* __restrict__ cnt,
              const int* __restrict__ srcs, const float* __restrict__ dinv,
              unsigned short* __restrict__ t_out, unsigned short* __restrict__ u_out, int n) {
  int wid = blockIdx.x * 4 + (threadIdx.x >> 6);
  if (wid >= n) return;
  int lane = threadIdx.x & 63;
  int rs = rowstart[wid], c = cnt[wid];
  float a = 0.f;
  int j = 0;
  for (; j + 8 <= c; j += 8) {
    int s0 = srcs[rs + j],     s1 = srcs[rs + j + 1], s2 = srcs[rs + j + 2], s3 = srcs[rs + j + 3];
    int s4 = srcs[rs + j + 4], s5 = srcs[rs + j + 5], s6 = srcs[rs + j + 6], s7 = srcs[rs + j + 7];
    float v0 = bf2f(U16[s0 * 64 + lane]);
    float v1 = bf2f(U16[s1 * 64 + lane]);
    float v2 = bf2f(U16[s2 * 64 + lane]);
    float v3 = bf2f(U16[s3 * 64 + lane]);
    float v4 = bf2f(U16[s4 * 64 + lane]);
    float v5 = bf2f(U16[s5 * 64 + lane]);
    float v6 = bf2f(U16[s6 * 64 + lane]);
    float v7 = bf2f(U16[s7 * 64 + lane]);
    a += ((v0 + v1) + (v2 + v3)) + ((v4 + v5) + (v6 + v7));
  }
  for (; j < c; j++) a += bf2f(U16[srcs[rs + j] * 64 + lane]);
  float dv = dinv[wid];
  float t = dv * a;
  t_out[wid * 64 + lane] = f2bf(t);
  if (u_out) u_out[wid * 64 + lane] = f2bf(dv * t);
}

// ====================== Fused MM building blocks (512 threads, 2 nodes x 4 feats) ======================

__device__ __forceinline__ void mm_zero2(float acc[2][4]) {
#pragma unroll
  for (int j = 0; j < 2; j++)
#pragma unroll
    for (int jj = 0; jj < 4; jj++) acc[j][jj] = 0.f;
}

__device__ __forceinline__ void mm_acc2(const float* sA, const float* sW, int K,
                                        int nl0, int f0, float acc[2][4]) {
  for (int k = 0; k < K; k++) {
    float4 w = *(const float4*)(&sW[k * 64 + f0]);
#pragma unroll
    for (int j = 0; j < 2; j++) {
      float a = sA[(nl0 + j) * 68 + k];
      acc[j][0] += a * w.x; acc[j][1] += a * w.y; acc[j][2] += a * w.z; acc[j][3] += a * w.w;
    }
  }
}

__device__ __forceinline__ void mm_loadw512(float* Ws, const float* W, int tid) {
  const float4* w4 = (const float4*)W;
  float4* s4 = (float4*)Ws;
  for (int i = tid; i < 1024; i += 512) s4[i] = w4[i];
}

__device__ __forceinline__ void mm_stage_f32_512(float* as, const float* A, const int* cntA,
                                                 int gb, int n, int tid) {
  for (int i = tid; i < 1024; i += 512) {
    int nl = i >> 4, k4 = i & 15;
    int g = gb + nl;
    float4 v = make_float4(0.f, 0.f, 0.f, 0.f);
    if (g < n) {
      v = ((const float4*)A)[g * 16 + k4];
      if (cntA) {
        float sc = 1.0f / fmaxf((float)cntA[g], 1.0f);
        v.x *= sc; v.y *= sc; v.z *= sc; v.w *= sc;
      }
    }
    *(float4*)(&as[nl * 68 + k4 * 4]) = v;
  }
}

__device__ __forceinline__ void mm_stage_bf16_512(float* as, const unsigned short* A,
                                                  int gb, int n, int tid) {
  for (int i = tid; i < 1024; i += 512) {
    int nl = i >> 4, k4 = i & 15;
    int g = gb + nl;
    float4 v = make_float4(0.f, 0.f, 0.f, 0.f);
    if (g < n) {
      uint2 u = ((const uint2*)(A + (size_t)g * 64))[k4];
      v.x = bf2f((unsigned short)(u.x & 0xFFFF));
      v.y = bf2f((unsigned short)(u.x >> 16));
      v.z = bf2f((unsigned short)(u.y & 0xFFFF));
      v.w = bf2f((unsigned short)(u.y >> 16));
    }
    *(float4*)(&as[nl * 68 + k4 * 4]) = v;
  }
}

// ---- phase-C chain (512 threads): S2 = relu(...chain of 4 MMs...) ----
__global__ __launch_bounds__(512, 6)
void k_mm_chainC(const float* __restrict__ aggHw, const float* __restrict__ state_x,
                 const float* __restrict__ aggHu, const int* __restrict__ cnt_h,
                 const float* __restrict__ aggIN, const int* __restrict__ cnt_in,
                 const float* __restrict__ W3_rel, const float* __restrict__ W3_root,
                 const float* __restrict__ b3,
                 const float* __restrict__ W32_l, const float* __restrict__ W32_r,
                 const float* __restrict__ b32,
                 const float* __restrict__ W4_l, const float* __restrict__ W4_r,
                 const float* __restrict__ b4,
                 const float* __restrict__ W42_l, const float* __restrict__ W42_r,
                 const float* __restrict__ b42,
                 float* __restrict__ S2out, unsigned short* __restrict__ S2b,
                 const float* __restrict__ dinvS, int n) {
  __shared__ float Ws[4096];
  __shared__ float as[64 * 68];
  __shared__ float cs[64 * 68];
  const int tid = threadIdx.x;
  const int gb = blockIdx.x * 64;
  const int f0 = (tid & 15) * 4;
  const int nl0 = (tid >> 4) * 2;
  float acc[2][4];

  // --- C1: aggHw@W3_rel + state_x@W3_root + b3, relu -> cs ---
  mm_loadw512(Ws, W3_rel, tid);
  mm_stage_f32_512(as, aggHw, nullptr, gb, n, tid);
  __syncthreads();
  mm_zero2(acc);
  mm_acc2(as, Ws, 64, nl0, f0, acc);
  __syncthreads();
  for (int i = tid; i < 320; i += 512) {
    int nl = i / 5, k = i - nl * 5;
    int g = gb + nl;
    as[nl * 68 + k] = (g < n) ? state_x[(size_t)g * 5 + k] : 0.f;
  }
  for (int i = tid; i < 320; i += 512) Ws[i] = W3_root[i];
  __syncthreads();
  mm_acc2(as, Ws, 5, nl0, f0, acc);
#pragma unroll
  for (int j = 0; j < 2; j++)
#pragma unroll
    for (int jj = 0; jj < 4; jj++)
      cs[(nl0 + j) * 68 + f0 + jj] = fmaxf(acc[j][jj] + b3[f0 + jj], 0.f);
  __syncthreads();

  // --- C2: aggHu'@W32_l + cs@W32_r + b32, relu -> cs ---
  mm_loadw512(Ws, W32_l, tid);
  mm_stage_f32_512(as, aggHu, cnt_h, gb, n, tid);
  __syncthreads();
  mm_zero2(acc);
  mm_acc2(as, Ws, 64, nl0, f0, acc);
  __syncthreads();
  mm_loadw512(Ws, W32_r, tid);
  __syncthreads();
  mm_acc2(cs, Ws, 64, nl0, f0, acc);
  __syncthreads();
#pragma unroll
  for (int j = 0; j < 2; j++)
#pragma unroll
    for (int jj = 0; jj < 4; jj++)
      cs[(nl0 + j) * 68 + f0 + jj] = fmaxf(acc[j][jj] + b32[f0 + jj], 0.f);
  __syncthreads();

  // --- C3: aggIN'@W4_l + cs@W4_r + b4, relu -> cs ---
  mm_loadw512(Ws, W4_l, tid);
  mm_stage_f32_512(as, aggIN, cnt_in, gb, n, tid);
  __syncthreads();
  mm_zero2(acc);
  mm_acc2(as, Ws, 64, nl0, f0, acc);
  __syncthreads();
  mm_loadw512(Ws, W4_r, tid);
  __syncthreads();
  mm_acc2(cs, Ws, 64, nl0, f0, acc);
  __syncthreads();
#pragma unroll
  for (int j = 0; j < 2; j++)
#pragma unroll
    for (int jj = 0; jj < 4; jj++)
      cs[(nl0 + j) * 68 + f0 + jj] = fmaxf(acc[j][jj] + b4[f0 + jj], 0.f);
  __syncthreads();

  // --- C4: aggIN'@W42_l + cs@W42_r + b42, relu -> S2 + S2b(dinv-scaled) ---
  mm_loadw512(Ws, W42_l, tid);
  mm_stage_f32_512(as, aggIN, cnt_in, gb, n, tid);
  __syncthreads();
  mm_zero2(acc);
  mm_acc2(as, Ws, 64, nl0, f0, acc);
  __syncthreads();
  mm_loadw512(Ws, W42_r, tid);
  __syncthreads();
  mm_acc2(cs, Ws, 64, nl0, f0, acc);
#pragma unroll
  for (int j = 0; j < 2; j++) {
    int g = gb + nl0 + j;
    if (g < n) {
      float osc = dinvS[g];
#pragma unroll
      for (int jj = 0; jj < 4; jj++) {
        int f = f0 + jj;
        float v = fmaxf(acc[j][jj] + b42[f], 0.f);
        S2out[(size_t)g * 64 + f] = v;
        S2b[(size_t)g * 64 + f] = f2bf(v * osc);
      }
    }
  }
}

// ---- phase-D quad MM (512 threads; NOTE: min-waves 6 not 8 — 8 forced a 64-VGPR
//      budget, compiler capped at 32 and spilled acc to scratch: 4 GB traffic, 1.5 ms) ----
__global__ __launch_bounds__(512, 6)
void k_mm_d(const float* __restrict__ S2, const unsigned short* __restrict__ t1b,
            const unsigned short* __restrict__ t2b, const unsigned short* __restrict__ t3b,
            const float* __restrict__ W2, const float* __restrict__ b2,
            float* __restrict__ S1, unsigned short* __restrict__ S1b, int n) {
  __shared__ float Ws[4096];
  __shared__ float as[64 * 68];
  const int tid = threadIdx.x;
  const int gb = blockIdx.x * 64;
  const int f0 = (tid & 15) * 4;
  const int nl0 = (tid >> 4) * 2;
  float acc[2][4];
  mm_zero2(acc);
  mm_loadw512(Ws, W2, tid);
  mm_stage_f32_512(as, S2, nullptr, gb, n, tid);
  __syncthreads();
  mm_acc2(as, Ws, 64, nl0, f0, acc);
  __syncthreads();
  mm_loadw512(Ws, W2 + 4096, tid);
  mm_stage_bf16_512(as, t1b, gb, n, tid);
  __syncthreads();
  mm_acc2(as, Ws, 64, nl0, f0, acc);
  __syncthreads();
  mm_loadw512(Ws, W2 + 8192, tid);
  mm_stage_bf16_512(as, t2b, gb, n, tid);
  __syncthreads();
  mm_acc2(as, Ws, 64, nl0, f0, acc);
  __syncthreads();
  mm_loadw512(Ws, W2 + 12288, tid);
  mm_stage_bf16_512(as, t3b, gb, n, tid);
  __syncthreads();
  mm_acc2(as, Ws, 64, nl0, f0, acc);
#pragma unroll
  for (int j = 0; j < 2; j++) {
    int g = gb + nl0 + j;
    if (g < n) {
#pragma unroll
      for (int jj = 0; jj < 4; jj++) {
        int f = f0 + jj;
        float v = fmaxf(acc[j][jj] + b2[f], 0.f);
        S1[(size_t)g * 64 + f] = v;
        S1b[(size_t)g * 64 + f] = f2bf(v);
      }
    }
  }
}

// ---- phase-E MM + final projection (512 threads) ----
__global__ __launch_bounds__(512, 6)
void k_mm_e(const float* __restrict__ aggSS, const int* __restrict__ cnt_ss,
            const float* __restrict__ W5_l, const float* __restrict__ S1,
            const float* __restrict__ W5_r, const float* __restrict__ b5,
            const float* __restrict__ Wl, const float* __restrict__ bl,
            float* __restrict__ out, int n) {
  __shared__ float Ws[4096];
  __shared__ float as[64 * 68];
  __shared__ float cs[64 * 68];
  const int tid = threadIdx.x;
  const int gb = blockIdx.x * 64;
  const int f0 = (tid & 15) * 4;
  const int nl0 = (tid >> 4) * 2;
  float acc[2][4];
  mm_zero2(acc);
  mm_loadw512(Ws, W5_l, tid);
  mm_stage_f32_512(as, aggSS, cnt_ss, gb, n, tid);
  __syncthreads();
  mm_acc2(as, Ws, 64, nl0, f0, acc);
  __syncthreads();
  mm_loadw512(Ws, W5_r, tid);
  mm_stage_f32_512(cs, S1, nullptr, gb, n, tid);
  __syncthreads();
  mm_acc2(cs, Ws, 64, nl0, f0, acc);
  __syncthreads();
#pragma unroll
  for (int j = 0; j < 2; j++)
#pragma unroll
    for (int jj = 0; jj < 4; jj++)
      as[(nl0 + j) * 68 + f0 + jj] = fmaxf(acc[j][jj] + b5[f0 + jj], 0.f);
  for (int i = tid; i < 512; i += 512) Ws[i] = Wl[i];
  __syncthreads();
  {
    int nl = tid >> 3, o = tid & 7;
    int g = gb + nl;
    if (g < n) {
      float a2 = bl[o];
#pragma unroll 8
      for (int k = 0; k < 64; k++) a2 += as[nl * 68 + k] * Ws[k * 8 + o];
      out[(size_t)g * 8 + o] = a2;
    }
  }
}

// ---------------- Host ----------------

extern "C" void kernel_launch(void* const* d_in, const int* in_sizes, int n_in,
                              void* d_out, int out_size, void* d_ws, size_t ws_size,
                              hipStream_t stream) {
  const float* game_x  = (const float*)d_in[0];
  const float* state_x = (const float*)d_in[1];
  const int*   ei_vv   = (const int*)d_in[2];
  const int*   et_vv   = (const int*)d_in[3];
  const int*   ei_h    = (const int*)d_in[4];
  const float* ew_h    = (const float*)d_in[5];
  const int*   ei_in   = (const int*)d_in[6];
  const int*   ei_ss   = (const int*)d_in[7];
  const float* W1_rel  = (const float*)d_in[8];
  const float* W1_root = (const float*)d_in[9];
  const float* b1      = (const float*)d_in[10];
  const float* W12     = (const float*)d_in[11];
  const float* b12     = (const float*)d_in[12];
  const float* W2      = (const float*)d_in[13];
  const float* b2      = (const float*)d_in[14];
  const float* W3_rel  = (const float*)d_in[15];
  const float* W3_root = (const float*)d_in[16];
  const float* b3      = (const float*)d_in[17];
  const float* W32_l   = (const float*)d_in[18];
  const float* W32_r   = (const float*)d_in[19];
  const float* b32     = (const float*)d_in[20];
  const float* W4_l    = (const float*)d_in[21];
  const float* W4_r    = (const float*)d_in[22];
  const float* b4      = (const float*)d_in[23];
  const float* W42_l   = (const float*)d_in[24];
  const float* W42_r   = (const float*)d_in[25];
  const float* b42     = (const float*)d_in[26];
  const float* W5_l    = (const float*)d_in[27];
  const float* W5_r    = (const float*)d_in[28];
  const float* b5      = (const float*)d_in[29];
  const float* Wl      = (const float*)d_in[30];
  const float* bl      = (const float*)d_in[31];

  // Workspace (4B slots), peak 26.05M slots = 104.2 MiB.
  float* ws = (float*)d_ws;
  int*   cnt_all = (int*)(ws + 0);              // 250K (vv|h|in|ss)
  int*   rs_all  = (int*)(ws + 250000);         // 250K (graph-local values)
  int*   bcnt    = (int*)(ws + 500000);         // 512
  int*   bbase   = (int*)(ws + 500512);         // 512
  int*   cb      = (int*)(ws + 501024);         // 512
  int*   srcs_ss = (int*)(ws + 760000);         // 0.8M  (lives through phase E)
  float4* x_pad  = (float4*)(ws + 1600000);     // 800K
  float4* h1p    = (float4*)(ws + 2400000);
  float4* h2p    = (float4*)(ws + 3200000);
  float4* h3p    = (float4*)(ws + 4000000);
  float4* ra4all = (float4*)(ws + 4800000);     // [NVV][5] float4 = 2.0M slots -> 6.8M
  float* dinvS   = ws + 6800000;                // 50K
  unsigned short* gx16 = (unsigned short*)(ws + 6850000);  // 3.2M slots -> 10.05M
  unsigned* temp_vv    = (unsigned*)(ws + 6850000);        // 1.6M, overlays gx16 front (dead before combine)
  float* aggHw = ws + 10050000;                 // 3.2M
  float* aggHu = ws + 13250000;                 // 3.2M
  float* aggIN = ws + 16450000;                 // 3.2M
  float* S1    = ws + 19650000;                 // 3.2M
  float* S2    = ws + 22850000;                 // 3.2M -> ends 26.05M
  // fill temps overlay agg regions (dead until phase B):
  uint2*    temp_h  = (uint2*)aggHw;
  unsigned* temp_in = (unsigned*)(aggHw + 1600000);
  unsigned* temp_ss = (unsigned*)(aggHw + 2400000);
  // overlays (dead-before-write verified in stream order):
  unsigned short* S2b = (unsigned short*)(ws + 4800000);     // in ra4all region (dead after combine_gx)
  unsigned short* u1b = (unsigned short*)(aggHw + 1600000);  // hop1 aux; aggHw dead after chainC
  float*          aggSS = aggHw + 1600000;                   // phase E (after u1b dead)
  unsigned short* t1b = (unsigned short*)aggHu;              // aggHu dead after chainC
  unsigned short* t2b = (unsigned short*)(aggHu + 1600000);
  unsigned short* t3b = (unsigned short*)aggIN;              // aggIN dead after chainC
  unsigned short* S1b = (unsigned short*)(aggIN + 1600000);  // k_mm_d shadow
  unsigned* payload_vv = (unsigned*)S1;                      // dead after phase A
  unsigned short* u2b  = (unsigned short*)S1;                // hop2 aux; S1 written later by k_mm_d
  int2*     eh         = (int2*)S2;                          // dead after aggB; S2 written by chainC
  int*      srcs_in    = (int*)(S2 + 1600000);

  const int* src_vv = ei_vv;  const int* dst_vv = ei_vv + E_VV;
  const int* src_h  = ei_h;   const int* dst_h  = ei_h + E_H;
  const int* src_in = ei_in;  const int* dst_in = ei_in + E_IN;
  const int* src_ss = ei_ss;  const int* dst_ss = ei_ss + E_SS;

  auto nblk = [](long long n) { return dim3((unsigned)((n + 255) / 256)); };
  const int NB64 = (NSV + 3) / 4;
  const int NB   = (NSV + 63) / 64;
  const int GC   = (ETOT + TC - 1) / TC;

  int* cnt_h  = cnt_all + H_ROW;
  int* cnt_in = cnt_all + IN_ROW;
  int* cnt_ss = cnt_all + SS_ROW;
  int* rs_vv  = rs_all;
  int* rs_h   = rs_all + H_ROW;
  int* rs_in  = rs_all + IN_ROW;
  int* rs_ss  = rs_all + SS_ROW;

  // ---- CSR build (fused) ----
  hipMemsetAsync(bcnt, 0, NBTOT * sizeof(int), stream);
  k_bucket_count<<<GC, 256, 0, stream>>>(dst_vv, dst_h, dst_in, dst_ss, bcnt);
  k_bucket_scan<<<1, 512, 0, stream>>>(bcnt, bbase, cb);
  k_fill_s1_all<<<SB1, 256, 0, stream>>>(src_vv, dst_vv, et_vv, src_h, dst_h, ew_h,
                                         src_in, dst_in, src_ss, dst_ss, cb,
                                         temp_vv, temp_h, temp_in, temp_ss);
  k_fill_s2_all<<<NBTOT, 256, 0, stream>>>(temp_vv, temp_h, temp_in, temp_ss, bbase,
                                           payload_vv, eh, srcs_in, srcs_ss,
                                           rs_all, cnt_all, game_x, x_pad, dinvS);

  // ---- Phase A: v-graph 5-dim ----
  k_vv_pass1<<<nblk(NVV), 256, 0, stream>>>(x_pad, rs_vv, cnt_all, payload_vv, ra4all, h1p);
  k_vv_hop<<<nblk(NVV), 256, 0, stream>>>(h1p, rs_vv, cnt_all, payload_vv, h2p);
  k_vv_hop<<<nblk(NVV), 256, 0, stream>>>(h2p, rs_vv, cnt_all, payload_vv, h3p);
  k_combine_gx<<<dim3((NVV + 31) / 32), 256, 0, stream>>>(x_pad, ra4all, h1p, h2p, h3p,
                                                          W1_rel, W1_root, b1, W12, b12, gx16);

  // ---- Phase B: fused 64-dim bf16 gathers ----
  k_aggB<<<2 * NB64, 256, 0, stream>>>(gx16, rs_h, cnt_h, eh, rs_in, cnt_in, srcs_in,
                                       aggHw, aggHu, aggIN, NB64);

  // ---- Phase C: fused 4-MM chain (512 threads) -> S2 (+ dinv-prescaled bf16 shadow) ----
  k_mm_chainC<<<NB, 512, 0, stream>>>(aggHw, state_x, aggHu, cnt_h, aggIN, cnt_in,
                                      W3_rel, W3_root, b3, W32_l, W32_r, b32,
                                      W4_l, W4_r, b4, W42_l, W42_r, b42,
                                      S2, S2b, dinvS, NSV);

  // ---- Phase D: TAG on s-s (prescaled bf16 hops) + fused quad MM ----
  k_tag64b<<<NB64, 256, 0, stream>>>(S2b, rs_ss, cnt_ss, srcs_ss, dinvS, t1b, u1b, NSV);
  k_tag64b<<<NB64, 256, 0, stream>>>(u1b, rs_ss, cnt_ss, srcs_ss, dinvS, t2b, u2b, NSV);
  k_tag64b<<<NB64, 256, 0, stream>>>(u2b, rs_ss, cnt_ss, srcs_ss, dinvS, t3b, nullptr, NSV);
  k_mm_d<<<NB, 512, 0, stream>>>(S2, t1b, t2b, t3b, W2, b2, S1, S1b, NSV);

  // ---- Phase E: SAGE on s-s + final projection ----
  k_agg64b<<<NB64, 256, 0, stream>>>(S1b, rs_ss, cnt_ss, srcs_ss, aggSS, NSV);
  k_mm_e<<<NB, 512, 0, stream>>>(aggSS, cnt_ss, W5_l, S1, W5_r, b5, Wl, bl, (float*)d_out, NSV);
}

// Round 14
// 3028.547 us; speedup vs baseline: 1.2596x; 1.2504x over previous
//
#include <hip/hip_runtime.h>

#define NVV 100000
#define NSV 50000
#define E_VV 1600000
#define E_H  800000
#define E_IN 800000
#define E_SS 800000
#define ETOT 4000000
#define DIN 5
#define H_ROW 100000          // concatenated cnt/rs space: vv|h|in|ss
#define IN_ROW 150000
#define SS_ROW 200000
#define NROWS 250000
#define POS_H  E_VV
#define POS_IN (E_VV + E_H)
#define POS_SS (E_VV + E_H + E_IN)
#define NBUK 196              // vv buckets (dst >> 9)
#define NBUKS 98              // NSV-graph buckets
#define NBTOT 490             // vv|h|in|ss bucket space
#define BUK_H  196
#define BUK_IN 294
#define BUK_SS 392
#define BSHIFT 9
#define T1 4096               // edges per fill-stage-1 block
#define TC 16384              // edges per bucket-count block
#define G1VV 391              // ceil(E_VV/T1)
#define G1S  196              // ceil(E_H/T1)
#define SB1  (G1VV + 3 * G1S) // 979 fused stage-1 blocks

__device__ __forceinline__ unsigned short f2bf(float x) {
  unsigned b = __float_as_uint(x);
  return (unsigned short)((b + 0x7FFFu + ((b >> 16) & 1u)) >> 16);
}
__device__ __forceinline__ float bf2f(unsigned short u) {
  return __uint_as_float(((unsigned)u) << 16);
}

// ====================== CSR build: bucket counts -> bases -> fused binned fills ======================

__global__ __launch_bounds__(256)
void k_bucket_count(const int* __restrict__ d_vv, const int* __restrict__ d_h,
                    const int* __restrict__ d_in, const int* __restrict__ d_ss,
                    int* __restrict__ bcnt) {
  __shared__ int h[NBTOT];
  const int tid = threadIdx.x;
  for (int i = tid; i < NBTOT; i += 256) h[i] = 0;
  __syncthreads();
  const int base = blockIdx.x * TC;
#pragma unroll 4
  for (int k = 0; k < TC / 256; k++) {
    int e = base + k * 256 + tid;
    int bi = -1;
    if (e < E_VV) bi = d_vv[e] >> BSHIFT;
    else if (e < POS_IN) bi = BUK_H + (d_h[e - POS_H] >> BSHIFT);
    else if (e < POS_SS) bi = BUK_IN + (d_in[e - POS_IN] >> BSHIFT);
    else if (e < ETOT) bi = BUK_SS + (d_ss[e - POS_SS] >> BSHIFT);
    if (bi >= 0) atomicAdd(&h[bi], 1);
  }
  __syncthreads();
  for (int i = tid; i < NBTOT; i += 256) if (h[i]) atomicAdd(&bcnt[i], h[i]);
}

__global__ __launch_bounds__(512)
void k_bucket_scan(const int* __restrict__ bcnt, int* __restrict__ bbase, int* __restrict__ cb) {
  __shared__ int sd[512];
  int t = threadIdx.x;
  int v = (t < NBTOT) ? bcnt[t] : 0;
  sd[t] = v; __syncthreads();
  for (int off = 1; off < 512; off <<= 1) {
    int x = (t >= off) ? sd[t - off] : 0;
    __syncthreads();
    sd[t] += x;
    __syncthreads();
  }
  int segstart = (t < BUK_H) ? 0 : (t < BUK_IN) ? BUK_H : (t < BUK_SS) ? BUK_IN : BUK_SS;
  int excl = ((t > 0) ? sd[t - 1] : 0) - ((segstart > 0) ? sd[segstart - 1] : 0);
  if (t < NBTOT) { bbase[t] = excl; cb[t] = excl; }
}

// ---- fused stage 1: all 4 graphs, bucket-grouped binning, coalesced run writes ----
__global__ __launch_bounds__(256)
void k_fill_s1_all(const int* __restrict__ s_vv, const int* __restrict__ d_vv,
                   const int* __restrict__ et,
                   const int* __restrict__ s_h, const int* __restrict__ d_h,
                   const float* __restrict__ ew,
                   const int* __restrict__ s_in, const int* __restrict__ d_in,
                   const int* __restrict__ s_ss, const int* __restrict__ d_ss,
                   int* __restrict__ cb,
                   unsigned* __restrict__ temp_vv, uint2* __restrict__ temp_h,
                   unsigned* __restrict__ temp_in, unsigned* __restrict__ temp_ss) {
  __shared__ int hist[NBUK], lbase[NBUK], run[NBUK], gb[NBUK];
  __shared__ int sc[256];
  __shared__ unsigned stage[T1];
  __shared__ unsigned stageW[T1];
  __shared__ int gpos[T1];
  const int tid = threadIdx.x;
  const int b = blockIdx.x;
  int g, tile;
  if (b < G1VV) { g = 0; tile = b; }
  else if (b < G1VV + G1S) { g = 1; tile = b - G1VV; }
  else if (b < G1VV + 2 * G1S) { g = 2; tile = b - G1VV - G1S; }
  else { g = 3; tile = b - G1VV - 2 * G1S; }
  const int ne = (g == 0) ? E_VV : E_H;
  const int nbuk = (g == 0) ? NBUK : NBUKS;
  const int cboff = (g == 0) ? 0 : (g == 1) ? BUK_H : (g == 2) ? BUK_IN : BUK_SS;
  const int* S = (g == 0) ? s_vv : (g == 1) ? s_h : (g == 2) ? s_in : s_ss;
  const int* D = (g == 0) ? d_vv : (g == 1) ? d_h : (g == 2) ? d_in : d_ss;
  const int base = tile * T1;
  const int nvalid = min(T1, ne - base);
  for (int i = tid; i < nbuk; i += 256) { hist[i] = 0; run[i] = 0; }
  __syncthreads();
  int dv[16]; unsigned pk[16], pkw[16];
#pragma unroll
  for (int k = 0; k < 16; k++) {
    int e = base + k * 256 + tid;
    if (e - base < nvalid) {
      int d = D[e];
      dv[k] = d;
      if (g == 0) pk[k] = (unsigned)(((d & 511) << 19) | (et[e] << 17) | S[e]);
      else pk[k] = (unsigned)(((d & 511) << 17) | S[e]);
      if (g == 1) pkw[k] = (unsigned)__float_as_int(ew[e]);
      atomicAdd(&hist[d >> BSHIFT], 1);
    } else dv[k] = -1;
  }
  __syncthreads();
  int my = (tid < nbuk) ? hist[tid] : 0;
  sc[tid] = my; __syncthreads();
  for (int off = 1; off < 256; off <<= 1) {
    int t = (tid >= off) ? sc[tid - off] : 0;
    __syncthreads();
    sc[tid] += t;
    __syncthreads();
  }
  if (tid < nbuk) {
    lbase[tid] = sc[tid] - my;
    gb[tid] = my ? atomicAdd(&cb[cboff + tid], my) : 0;
  }
  __syncthreads();
#pragma unroll
  for (int k = 0; k < 16; k++) {
    if (dv[k] >= 0) {
      int bu = dv[k] >> BSHIFT;
      int loc = atomicAdd(&run[bu], 1);
      int li = lbase[bu] + loc;
      stage[li] = pk[k];
      if (g == 1) stageW[li] = pkw[k];
      gpos[li] = gb[bu] + loc;
    }
  }
  __syncthreads();
  if (g == 0)      for (int i = tid; i < nvalid; i += 256) temp_vv[gpos[i]] = stage[i];
  else if (g == 1) for (int i = tid; i < nvalid; i += 256) temp_h[gpos[i]] = make_uint2(stage[i], stageW[i]);
  else if (g == 2) for (int i = tid; i < nvalid; i += 256) temp_in[gpos[i]] = stage[i];
  else             for (int i = tid; i < nvalid; i += 256) temp_ss[gpos[i]] = stage[i];
}

// ---- fused stage 2 ----
__global__ __launch_bounds__(256)
void k_fill_s2_all(const unsigned* __restrict__ temp_vv, const uint2* __restrict__ temp_h,
                   const unsigned* __restrict__ temp_in, const unsigned* __restrict__ temp_ss,
                   const int* __restrict__ bbase,
                   unsigned* __restrict__ payload_vv, int2* __restrict__ eh,
                   int* __restrict__ srcs_in, int* __restrict__ srcs_ss,
                   int* __restrict__ rs_all, int* __restrict__ cnt_all,
                   const float* __restrict__ x, float4* __restrict__ xp,
                   float* __restrict__ dinvS) {
  __shared__ int lcnt[512], lpos[512];
  __shared__ int sc[256];
  const int b = blockIdx.x, tid = threadIdx.x;
  int g, lb;
  if (b < BUK_H) { g = 0; lb = b; }
  else if (b < BUK_IN) { g = 1; lb = b - BUK_H; }
  else if (b < BUK_SS) { g = 2; lb = b - BUK_IN; }
  else { g = 3; lb = b - BUK_SS; }
  const int d0 = lb << BSHIFT;
  const int nrows = (g == 0) ? NVV : NSV;
  const int rowbase = (g == 0) ? 0 : (g == 1) ? H_ROW : (g == 2) ? IN_ROW : SS_ROW;
  const int ne = (g == 0) ? E_VV : E_H;
  const int lastb = (g == 0) ? NBUK - 1 : NBUKS - 1;
  const int shift = (g == 0) ? 19 : 17;
  lcnt[tid] = 0; lcnt[tid + 256] = 0;
  __syncthreads();
  const int gstart = bbase[b];
  const int gend = (lb == lastb) ? ne : bbase[b + 1];
  if (g == 1) {
    for (int i = gstart + tid; i < gend; i += 256) atomicAdd(&lcnt[temp_h[i].x >> 17], 1);
  } else {
    const unsigned* tp = (g == 0) ? temp_vv : (g == 2) ? temp_in : temp_ss;
    for (int i = gstart + tid; i < gend; i += 256) atomicAdd(&lcnt[tp[i] >> shift], 1);
  }
  __syncthreads();
  int c0 = lcnt[2 * tid], c1 = lcnt[2 * tid + 1];
  int ps = c0 + c1;
  sc[tid] = ps; __syncthreads();
  for (int off = 1; off < 256; off <<= 1) {
    int x2 = (tid >= off) ? sc[tid - off] : 0;
    __syncthreads();
    sc[tid] += x2;
    __syncthreads();
  }
  int basep = gstart + sc[tid] - ps;
  lpos[2 * tid] = basep;
  lpos[2 * tid + 1] = basep + c0;
  __syncthreads();
  for (int d = tid; d < 512; d += 256) {
    int gd = d0 + d;
    if (gd < nrows) {
      rs_all[rowbase + gd] = lpos[d];
      cnt_all[rowbase + gd] = lcnt[d];
      if (g == 0) {
        float dc = (float)lcnt[d];
        float di = dc > 0.f ? rsqrtf(dc) : 0.f;
        const float* xr = x + (size_t)gd * 5;
        xp[gd * 2]     = make_float4(xr[0], xr[1], xr[2], xr[3]);
        xp[gd * 2 + 1] = make_float4(xr[4], di, 0.f, 0.f);
      } else if (g == 3) {
        float dc = (float)lcnt[d];
        dinvS[gd] = dc > 0.f ? rsqrtf(dc) : 0.f;
      }
    }
  }
  __syncthreads();
  if (g == 0) {
    for (int i = gstart + tid; i < gend; i += 256) {
      unsigned en = temp_vv[i];
      int pos = atomicAdd(&lpos[en >> 19], 1);
      payload_vv[pos] = en & 0x7FFFFu;
    }
  } else if (g == 1) {
    for (int i = gstart + tid; i < gend; i += 256) {
      uint2 en = temp_h[i];
      int pos = atomicAdd(&lpos[en.x >> 17], 1);
      eh[pos] = make_int2((int)(en.x & 0x1FFFFu), (int)en.y);
    }
  } else if (g == 2) {
    for (int i = gstart + tid; i < gend; i += 256) {
      unsigned en = temp_in[i];
      int pos = atomicAdd(&lpos[en >> 17], 1);
      srcs_in[pos] = (int)(en & 0x1FFFFu);
    }
  } else {
    for (int i = gstart + tid; i < gend; i += 256) {
      unsigned en = temp_ss[i];
      int pos = atomicAdd(&lpos[en >> 17], 1);
      srcs_ss[pos] = (int)(en & 0x1FFFFu);
    }
  }
}

// ====================== Phase A: v-graph (5-dim, padded rows) ======================

__global__ __launch_bounds__(256)
void k_vv_pass1(const float4* __restrict__ xp,
                const int* __restrict__ rowstart, const int* __restrict__ cnt,
                const unsigned* __restrict__ payload,
                float4* __restrict__ ra4all, float4* __restrict__ h1p) {
  int d = blockIdx.x * 256 + threadIdx.x;
  if (d >= NVV) return;
  int rs = rowstart[d], c = cnt[d];
  float a0[5] = {0,0,0,0,0}, a1[5] = {0,0,0,0,0}, a2[5] = {0,0,0,0,0}, h[5] = {0,0,0,0,0};
  float c0 = 0.f, c1 = 0.f, c2 = 0.f;
  int j = 0;
  for (; j + 2 <= c; j += 2) {
    unsigned pA = payload[rs + j], pB = payload[rs + j + 1];
    int sA = pA & 0x1FFFF, rA = pA >> 17;
    int sB = pB & 0x1FFFF, rB = pB >> 17;
    float4 xA0 = xp[sA * 2], xA1 = xp[sA * 2 + 1];
    float4 xB0 = xp[sB * 2], xB1 = xp[sB * 2 + 1];
    float xsA[5] = {xA0.x, xA0.y, xA0.z, xA0.w, xA1.x};
    float xsB[5] = {xB0.x, xB0.y, xB0.z, xB0.w, xB1.x};
    float wA = xA1.y, wB = xB1.y;
    float mA0 = (rA == 0) ? 1.f : 0.f, mA1 = (rA == 1) ? 1.f : 0.f, mA2 = (rA == 2) ? 1.f : 0.f;
    float mB0 = (rB == 0) ? 1.f : 0.f, mB1 = (rB == 1) ? 1.f : 0.f, mB2 = (rB == 2) ? 1.f : 0.f;
    c0 += mA0 + mB0; c1 += mA1 + mB1; c2 += mA2 + mB2;
#pragma unroll
    for (int k = 0; k < 5; k++) {
      h[k] += wA * xsA[k] + wB * xsB[k];
      a0[k] += mA0 * xsA[k] + mB0 * xsB[k];
      a1[k] += mA1 * xsA[k] + mB1 * xsB[k];
      a2[k] += mA2 * xsA[k] + mB2 * xsB[k];
    }
  }
  for (; j < c; j++) {
    unsigned p = payload[rs + j];
    int s = p & 0x1FFFF, r = p >> 17;
    float4 x0 = xp[s * 2], x1 = xp[s * 2 + 1];
    float xs[5] = {x0.x, x0.y, x0.z, x0.w, x1.x};
    float wsc = x1.y;
    float m0 = (r == 0) ? 1.f : 0.f, m1 = (r == 1) ? 1.f : 0.f, m2 = (r == 2) ? 1.f : 0.f;
    c0 += m0; c1 += m1; c2 += m2;
#pragma unroll
    for (int k = 0; k < 5; k++) {
      h[k] += wsc * xs[k];
      a0[k] += m0 * xs[k]; a1[k] += m1 * xs[k]; a2[k] += m2 * xs[k];
    }
  }
  float dv = xp[d * 2 + 1].y;
  float4* ra4 = ra4all + d * 5;
  ra4[0] = make_float4(a0[0], a0[1], a0[2], a0[3]);
  ra4[1] = make_float4(a0[4], a1[0], a1[1], a1[2]);
  ra4[2] = make_float4(a1[3], a1[4], a2[0], a2[1]);
  ra4[3] = make_float4(a2[2], a2[3], a2[4], c0);
  ra4[4] = make_float4(c1, c2, 0.f, 0.f);
  h1p[d * 2]     = make_float4(dv * h[0], dv * h[1], dv * h[2], dv * h[3]);
  h1p[d * 2 + 1] = make_float4(dv * h[4], dv, 0.f, 0.f);
}

__global__ __launch_bounds__(256)
void k_vv_hop(const float4* __restrict__ hinp,
              const int* __restrict__ rowstart, const int* __restrict__ cnt,
              const unsigned* __restrict__ payload, float4* __restrict__ houtp) {
  int d = blockIdx.x * 256 + threadIdx.x;
  if (d >= NVV) return;
  int rs = rowstart[d], c = cnt[d];
  float h[5] = {0,0,0,0,0};
  int j = 0;
  for (; j + 4 <= c; j += 4) {
    unsigned p0 = payload[rs + j], p1 = payload[rs + j + 1];
    unsigned p2 = payload[rs + j + 2], p3 = payload[rs + j + 3];
    int s0 = p0 & 0x1FFFF, s1 = p1 & 0x1FFFF, s2 = p2 & 0x1FFFF, s3 = p3 & 0x1FFFF;
    float4 a0 = hinp[s0 * 2], b0 = hinp[s0 * 2 + 1];
    float4 a1 = hinp[s1 * 2], b1 = hinp[s1 * 2 + 1];
    float4 a2 = hinp[s2 * 2], b2 = hinp[s2 * 2 + 1];
    float4 a3 = hinp[s3 * 2], b3 = hinp[s3 * 2 + 1];
    float w0 = b0.y, w1 = b1.y, w2 = b2.y, w3 = b3.y;
    h[0] += w0 * a0.x + w1 * a1.x + w2 * a2.x + w3 * a3.x;
    h[1] += w0 * a0.y + w1 * a1.y + w2 * a2.y + w3 * a3.y;
    h[2] += w0 * a0.z + w1 * a1.z + w2 * a2.z + w3 * a3.z;
    h[3] += w0 * a0.w + w1 * a1.w + w2 * a2.w + w3 * a3.w;
    h[4] += w0 * b0.x + w1 * b1.x + w2 * b2.x + w3 * b3.x;
  }
  for (; j < c; j++) {
    int s = payload[rs + j] & 0x1FFFF;
    float4 x0 = hinp[s * 2], x1 = hinp[s * 2 + 1];
    float wsc = x1.y;
    h[0] += wsc * x0.x; h[1] += wsc * x0.y; h[2] += wsc * x0.z; h[3] += wsc * x0.w;
    h[4] += wsc * x1.x;
  }
  float dv = hinp[d * 2 + 1].y;
  houtp[d * 2]     = make_float4(dv * h[0], dv * h[1], dv * h[2], dv * h[3]);
  houtp[d * 2 + 1] = make_float4(dv * h[4], dv, 0.f, 0.f);
}

// 8 nodes/thread, Ws column in 35 VGPRs, float4 relall loads.
__global__ __launch_bounds__(256)
void k_combine_gx(const float4* __restrict__ xp,
                  const float4* __restrict__ ra4all,
                  const float4* __restrict__ h1p, const float4* __restrict__ h2p,
                  const float4* __restrict__ h3p,
                  const float* __restrict__ W1_rel, const float* __restrict__ W1_root,
                  const float* __restrict__ b1,
                  const float* __restrict__ W12, const float* __restrict__ b12,
                  unsigned short* __restrict__ gx16) {
  __shared__ float Ws[7 * 320];
  __shared__ float bs[64];
  int tid = threadIdx.x;
  for (int i = tid; i < 320; i += 256) {
    Ws[i]        = W1_root[i] + W12[i];
    Ws[320 + i]  = W1_rel[i];
    Ws[640 + i]  = W1_rel[320 + i];
    Ws[960 + i]  = W1_rel[640 + i];
    Ws[1280 + i] = W12[320 + i];
    Ws[1600 + i] = W12[640 + i];
    Ws[1920 + i] = W12[960 + i];
  }
  if (tid < 64) bs[tid] = b1[tid] + b12[tid];
  __syncthreads();
  const int f = tid & 63;
  const int grp = tid >> 6;
  float wcol[35];
#pragma unroll
  for (int t = 0; t < 35; t++) wcol[t] = Ws[t * 64 + f];
  const float bias = bs[f];
  const int v0 = blockIdx.x * 32 + grp * 8;
  for (int n = 0; n < 8; n++) {
    int v = v0 + n;
    if (v >= NVV) return;
    float in[35];
    {
      float4 x0 = xp[v * 2], x1 = xp[v * 2 + 1];
      in[0] = x0.x; in[1] = x0.y; in[2] = x0.z; in[3] = x0.w; in[4] = x1.x;
    }
    {
      const float4* ra = ra4all + v * 5;
      float4 r0 = ra[0], r1 = ra[1], r2 = ra[2], r3 = ra[3], r4 = ra[4];
      float i0 = 1.0f / fmaxf(r3.w, 1.0f);
      float i1 = 1.0f / fmaxf(r4.x, 1.0f);
      float i2 = 1.0f / fmaxf(r4.y, 1.0f);
      in[5]  = r0.x * i0; in[6]  = r0.y * i0; in[7]  = r0.z * i0; in[8]  = r0.w * i0; in[9]  = r1.x * i0;
      in[10] = r1.y * i1; in[11] = r1.z * i1; in[12] = r1.w * i1; in[13] = r2.x * i1; in[14] = r2.y * i1;
      in[15] = r2.z * i2; in[16] = r2.w * i2; in[17] = r3.x * i2; in[18] = r3.y * i2; in[19] = r3.z * i2;
    }
    {
      float4 a = h1p[v * 2], b = h1p[v * 2 + 1];
      in[20] = a.x; in[21] = a.y; in[22] = a.z; in[23] = a.w; in[24] = b.x;
      a = h2p[v * 2]; b = h2p[v * 2 + 1];
      in[25] = a.x; in[26] = a.y; in[27] = a.z; in[28] = a.w; in[29] = b.x;
      a = h3p[v * 2]; b = h3p[v * 2 + 1];
      in[30] = a.x; in[31] = a.y; in[32] = a.z; in[33] = a.w; in[34] = b.x;
    }
    float acc = bias;
#pragma unroll
    for (int t = 0; t < 35; t++) acc += in[t] * wcol[t];
    gx16[v * 64 + f] = f2bf(acc);
  }
}

// ================= 64-dim CSR gathers (wave per dst, lane=feature, 8-way MLP) =================

__global__ __launch_bounds__(256)
void k_aggB(const unsigned short* __restrict__ X16,
            const int* __restrict__ rs_h, const int* __restrict__ cnt_h,
            const int2* __restrict__ eh,
            const int* __restrict__ rs_in, const int* __restrict__ cnt_in,
            const int* __restrict__ srcs_in,
            float* __restrict__ outw, float* __restrict__ outu, float* __restrict__ outIN,
            int nb64) {
  int bb = blockIdx.x;
  int lane = threadIdx.x & 63;
  if (bb < nb64) {
    int wid = bb * 4 + (threadIdx.x >> 6);
    if (wid >= NSV) return;
    int rs = rs_h[wid], c = cnt_h[wid];
    float aw = 0.f, au = 0.f;
    int j = 0;
    for (; j + 8 <= c; j += 8) {
      int2 p0 = eh[rs + j],     p1 = eh[rs + j + 1], p2 = eh[rs + j + 2], p3 = eh[rs + j + 3];
      int2 p4 = eh[rs + j + 4], p5 = eh[rs + j + 5], p6 = eh[rs + j + 6], p7 = eh[rs + j + 7];
      float v0 = bf2f(X16[p0.x * 64 + lane]);
      float v1 = bf2f(X16[p1.x * 64 + lane]);
      float v2 = bf2f(X16[p2.x * 64 + lane]);
      float v3 = bf2f(X16[p3.x * 64 + lane]);
      float v4 = bf2f(X16[p4.x * 64 + lane]);
      float v5 = bf2f(X16[p5.x * 64 + lane]);
      float v6 = bf2f(X16[p6.x * 64 + lane]);
      float v7 = bf2f(X16[p7.x * 64 + lane]);
      au += ((v0 + v1) + (v2 + v3)) + ((v4 + v5) + (v6 + v7));
      aw += __int_as_float(p0.y) * v0 + __int_as_float(p1.y) * v1
          + __int_as_float(p2.y) * v2 + __int_as_float(p3.y) * v3
          + __int_as_float(p4.y) * v4 + __int_as_float(p5.y) * v5
          + __int_as_float(p6.y) * v6 + __int_as_float(p7.y) * v7;
    }
    for (; j < c; j++) {
      int2 p = eh[rs + j];
      float v = bf2f(X16[p.x * 64 + lane]);
      au += v; aw += __int_as_float(p.y) * v;
    }
    outw[wid * 64 + lane] = aw;
    outu[wid * 64 + lane] = au;
  } else {
    int wid = (bb - nb64) * 4 + (threadIdx.x >> 6);
    if (wid >= NSV) return;
    int rs = rs_in[wid], c = cnt_in[wid];
    float a = 0.f;
    int j = 0;
    for (; j + 8 <= c; j += 8) {
      int s0 = srcs_in[rs + j],     s1 = srcs_in[rs + j + 1], s2 = srcs_in[rs + j + 2], s3 = srcs_in[rs + j + 3];
      int s4 = srcs_in[rs + j + 4], s5 = srcs_in[rs + j + 5], s6 = srcs_in[rs + j + 6], s7 = srcs_in[rs + j + 7];
      float v0 = bf2f(X16[s0 * 64 + lane]);
      float v1 = bf2f(X16[s1 * 64 + lane]);
      float v2 = bf2f(X16[s2 * 64 + lane]);
      float v3 = bf2f(X16[s3 * 64 + lane]);
      float v4 = bf2f(X16[s4 * 64 + lane]);
      float v5 = bf2f(X16[s5 * 64 + lane]);
      float v6 = bf2f(X16[s6 * 64 + lane]);
      float v7 = bf2f(X16[s7 * 64 + lane]);
      a += ((v0 + v1) + (v2 + v3)) + ((v4 + v5) + (v6 + v7));
    }
    for (; j < c; j++) a += bf2f(X16[srcs_in[rs + j] * 64 + lane]);
    outIN[wid * 64 + lane] = a;
  }
}

__global__ __launch_bounds__(256)
void k_agg64b(const unsigned short* __restrict__ X16,
              const int* __restrict__ rowstart, const int* __restrict__ cnt,
              const int* __restrict__ srcs, float* __restrict__ out, int n) {
  int wid = blockIdx.x * 4 + (threadIdx.x >> 6);
  if (wid >= n) return;
  int lane = threadIdx.x & 63;
  int rs = rowstart[wid], c = cnt[wid];
  float a = 0.f;
  int j = 0;
  for (; j + 8 <= c; j += 8) {
    int s0 = srcs[rs + j],     s1 = srcs[rs + j + 1], s2 = srcs[rs + j + 2], s3 = srcs[rs + j + 3];
    int s4 = srcs[rs + j + 4], s5 = srcs[rs + j + 5], s6 = srcs[rs + j + 6], s7 = srcs[rs + j + 7];
    float v0 = bf2f(X16[s0 * 64 + lane]);
    float v1 = bf2f(X16[s1 * 64 + lane]);
    float v2 = bf2f(X16[s2 * 64 + lane]);
    float v3 = bf2f(X16[s3 * 64 + lane]);
    float v4 = bf2f(X16[s4 * 64 + lane]);
    float v5 = bf2f(X16[s5 * 64 + lane]);
    float v6 = bf2f(X16[s6 * 64 + lane]);
    float v7 = bf2f(X16[s7 * 64 + lane]);
    a += ((v0 + v1) + (v2 + v3)) + ((v4 + v5) + (v6 + v7));
  }
  for (; j < c; j++) a += bf2f(X16[srcs[rs + j] * 64 + lane]);
  out[wid * 64 + lane] = a;
}

// prescaled TAG hop: U = dinv ⊙ t (bf16). t_out = dinv[d]*Σ U[s]; u_out = dinv[d]*t_out.
__global__ __launch_bounds__(256)
void k_tag64b(const unsigned short* __restrict__ U16,
              const int* __restrict__ rowstart, const int* __restrict__ cnt,
              const int* __restrict__ srcs, const float* __restrict__ dinv,
              unsigned short* __restrict__ t_out, unsigned short* __restrict__ u_out, int n) {
  int wid = blockIdx.x * 4 + (threadIdx.x >> 6);
  if (wid >= n) return;
  int lane = threadIdx.x & 63;
  int rs = rowstart[wid], c = cnt[wid];
  float a = 0.f;
  int j = 0;
  for (; j + 8 <= c; j += 8) {
    int s0 = srcs[rs + j],     s1 = srcs[rs + j + 1], s2 = srcs[rs + j + 2], s3 = srcs[rs + j + 3];
    int s4 = srcs[rs + j + 4], s5 = srcs[rs + j + 5], s6 = srcs[rs + j + 6], s7 = srcs[rs + j + 7];
    float v0 = bf2f(U16[s0 * 64 + lane]);
    float v1 = bf2f(U16[s1 * 64 + lane]);
    float v2 = bf2f(U16[s2 * 64 + lane]);
    float v3 = bf2f(U16[s3 * 64 + lane]);
    float v4 = bf2f(U16[s4 * 64 + lane]);
    float v5 = bf2f(U16[s5 * 64 + lane]);
    float v6 = bf2f(U16[s6 * 64 + lane]);
    float v7 = bf2f(U16[s7 * 64 + lane]);
    a += ((v0 + v1) + (v2 + v3)) + ((v4 + v5) + (v6 + v7));
  }
  for (; j < c; j++) a += bf2f(U16[srcs[rs + j] * 64 + lane]);
  float dv = dinv[wid];
  float t = dv * a;
  t_out[wid * 64 + lane] = f2bf(t);
  if (u_out) u_out[wid * 64 + lane] = f2bf(dv * t);
}

// ====================== Fused MM building blocks (512 threads, 2 nodes x 4 feats) ======================
// NOTE: no min-waves arg on these kernels. Empirically (r12/r13) __launch_bounds__(512,w)
// budgets VGPRs as 256/w on this compiler (w=8 -> 32 VGPR, w=6 -> 40 VGPR), forcing
// accumulator spill to scratch (~4 GB traffic, 1.5 ms). Occupancy is LDS-limited anyway
// (33-50 KB -> 3-4 blocks/CU = 24-32 waves), so let registers allocate naturally.

__device__ __forceinline__ void mm_zero2(float acc[2][4]) {
#pragma unroll
  for (int j = 0; j < 2; j++)
#pragma unroll
    for (int jj = 0; jj < 4; jj++) acc[j][jj] = 0.f;
}

__device__ __forceinline__ void mm_acc2(const float* sA, const float* sW, int K,
                                        int nl0, int f0, float acc[2][4]) {
  for (int k = 0; k < K; k++) {
    float4 w = *(const float4*)(&sW[k * 64 + f0]);
#pragma unroll
    for (int j = 0; j < 2; j++) {
      float a = sA[(nl0 + j) * 68 + k];
      acc[j][0] += a * w.x; acc[j][1] += a * w.y; acc[j][2] += a * w.z; acc[j][3] += a * w.w;
    }
  }
}

__device__ __forceinline__ void mm_loadw512(float* Ws, const float* W, int tid) {
  const float4* w4 = (const float4*)W;
  float4* s4 = (float4*)Ws;
  for (int i = tid; i < 1024; i += 512) s4[i] = w4[i];
}

__device__ __forceinline__ void mm_stage_f32_512(float* as, const float* A, const int* cntA,
                                                 int gb, int n, int tid) {
  for (int i = tid; i < 1024; i += 512) {
    int nl = i >> 4, k4 = i & 15;
    int g = gb + nl;
    float4 v = make_float4(0.f, 0.f, 0.f, 0.f);
    if (g < n) {
      v = ((const float4*)A)[g * 16 + k4];
      if (cntA) {
        float sc = 1.0f / fmaxf((float)cntA[g], 1.0f);
        v.x *= sc; v.y *= sc; v.z *= sc; v.w *= sc;
      }
    }
    *(float4*)(&as[nl * 68 + k4 * 4]) = v;
  }
}

__device__ __forceinline__ void mm_stage_bf16_512(float* as, const unsigned short* A,
                                                  int gb, int n, int tid) {
  for (int i = tid; i < 1024; i += 512) {
    int nl = i >> 4, k4 = i & 15;
    int g = gb + nl;
    float4 v = make_float4(0.f, 0.f, 0.f, 0.f);
    if (g < n) {
      uint2 u = ((const uint2*)(A + (size_t)g * 64))[k4];
      v.x = bf2f((unsigned short)(u.x & 0xFFFF));
      v.y = bf2f((unsigned short)(u.x >> 16));
      v.z = bf2f((unsigned short)(u.y & 0xFFFF));
      v.w = bf2f((unsigned short)(u.y >> 16));
    }
    *(float4*)(&as[nl * 68 + k4 * 4]) = v;
  }
}

// ---- phase-C chain (512 threads): S2 = relu(...chain of 4 MMs...) ----
__global__ __launch_bounds__(512)
void k_mm_chainC(const float* __restrict__ aggHw, const float* __restrict__ state_x,
                 const float* __restrict__ aggHu, const int* __restrict__ cnt_h,
                 const float* __restrict__ aggIN, const int* __restrict__ cnt_in,
                 const float* __restrict__ W3_rel, const float* __restrict__ W3_root,
                 const float* __restrict__ b3,
                 const float* __restrict__ W32_l, const float* __restrict__ W32_r,
                 const float* __restrict__ b32,
                 const float* __restrict__ W4_l, const float* __restrict__ W4_r,
                 const float* __restrict__ b4,
                 const float* __restrict__ W42_l, const float* __restrict__ W42_r,
                 const float* __restrict__ b42,
                 float* __restrict__ S2out, unsigned short* __restrict__ S2b,
                 const float* __restrict__ dinvS, int n) {
  __shared__ float Ws[4096];
  __shared__ float as[64 * 68];
  __shared__ float cs[64 * 68];
  const int tid = threadIdx.x;
  const int gb = blockIdx.x * 64;
  const int f0 = (tid & 15) * 4;
  const int nl0 = (tid >> 4) * 2;
  float acc[2][4];

  // --- C1: aggHw@W3_rel + state_x@W3_root + b3, relu -> cs ---
  mm_loadw512(Ws, W3_rel, tid);
  mm_stage_f32_512(as, aggHw, nullptr, gb, n, tid);
  __syncthreads();
  mm_zero2(acc);
  mm_acc2(as, Ws, 64, nl0, f0, acc);
  __syncthreads();
  for (int i = tid; i < 320; i += 512) {
    int nl = i / 5, k = i - nl * 5;
    int g = gb + nl;
    as[nl * 68 + k] = (g < n) ? state_x[(size_t)g * 5 + k] : 0.f;
  }
  for (int i = tid; i < 320; i += 512) Ws[i] = W3_root[i];
  __syncthreads();
  mm_acc2(as, Ws, 5, nl0, f0, acc);
#pragma unroll
  for (int j = 0; j < 2; j++)
#pragma unroll
    for (int jj = 0; jj < 4; jj++)
      cs[(nl0 + j) * 68 + f0 + jj] = fmaxf(acc[j][jj] + b3[f0 + jj], 0.f);
  __syncthreads();

  // --- C2: aggHu'@W32_l + cs@W32_r + b32, relu -> cs ---
  mm_loadw512(Ws, W32_l, tid);
  mm_stage_f32_512(as, aggHu, cnt_h, gb, n, tid);
  __syncthreads();
  mm_zero2(acc);
  mm_acc2(as, Ws, 64, nl0, f0, acc);
  __syncthreads();
  mm_loadw512(Ws, W32_r, tid);
  __syncthreads();
  mm_acc2(cs, Ws, 64, nl0, f0, acc);
  __syncthreads();
#pragma unroll
  for (int j = 0; j < 2; j++)
#pragma unroll
    for (int jj = 0; jj < 4; jj++)
      cs[(nl0 + j) * 68 + f0 + jj] = fmaxf(acc[j][jj] + b32[f0 + jj], 0.f);
  __syncthreads();

  // --- C3: aggIN'@W4_l + cs@W4_r + b4, relu -> cs ---
  mm_loadw512(Ws, W4_l, tid);
  mm_stage_f32_512(as, aggIN, cnt_in, gb, n, tid);
  __syncthreads();
  mm_zero2(acc);
  mm_acc2(as, Ws, 64, nl0, f0, acc);
  __syncthreads();
  mm_loadw512(Ws, W4_r, tid);
  __syncthreads();
  mm_acc2(cs, Ws, 64, nl0, f0, acc);
  __syncthreads();
#pragma unroll
  for (int j = 0; j < 2; j++)
#pragma unroll
    for (int jj = 0; jj < 4; jj++)
      cs[(nl0 + j) * 68 + f0 + jj] = fmaxf(acc[j][jj] + b4[f0 + jj], 0.f);
  __syncthreads();

  // --- C4: aggIN'@W42_l + cs@W42_r + b42, relu -> S2 + S2b(dinv-scaled) ---
  mm_loadw512(Ws, W42_l, tid);
  mm_stage_f32_512(as, aggIN, cnt_in, gb, n, tid);
  __syncthreads();
  mm_zero2(acc);
  mm_acc2(as, Ws, 64, nl0, f0, acc);
  __syncthreads();
  mm_loadw512(Ws, W42_r, tid);
  __syncthreads();
  mm_acc2(cs, Ws, 64, nl0, f0, acc);
#pragma unroll
  for (int j = 0; j < 2; j++) {
    int g = gb + nl0 + j;
    if (g < n) {
      float osc = dinvS[g];
#pragma unroll
      for (int jj = 0; jj < 4; jj++) {
        int f = f0 + jj;
        float v = fmaxf(acc[j][jj] + b42[f], 0.f);
        S2out[(size_t)g * 64 + f] = v;
        S2b[(size_t)g * 64 + f] = f2bf(v * osc);
      }
    }
  }
}

// ---- phase-D quad MM (512 threads) ----
__global__ __launch_bounds__(512)
void k_mm_d(const float* __restrict__ S2, const unsigned short* __restrict__ t1b,
            const unsigned short* __restrict__ t2b, const unsigned short* __restrict__ t3b,
            const float* __restrict__ W2, const float* __restrict__ b2,
            float* __restrict__ S1, unsigned short* __restrict__ S1b, int n) {
  __shared__ float Ws[4096];
  __shared__ float as[64 * 68];
  const int tid = threadIdx.x;
  const int gb = blockIdx.x * 64;
  const int f0 = (tid & 15) * 4;
  const int nl0 = (tid >> 4) * 2;
  float acc[2][4];
  mm_zero2(acc);
  mm_loadw512(Ws, W2, tid);
  mm_stage_f32_512(as, S2, nullptr, gb, n, tid);
  __syncthreads();
  mm_acc2(as, Ws, 64, nl0, f0, acc);
  __syncthreads();
  mm_loadw512(Ws, W2 + 4096, tid);
  mm_stage_bf16_512(as, t1b, gb, n, tid);
  __syncthreads();
  mm_acc2(as, Ws, 64, nl0, f0, acc);
  __syncthreads();
  mm_loadw512(Ws, W2 + 8192, tid);
  mm_stage_bf16_512(as, t2b, gb, n, tid);
  __syncthreads();
  mm_acc2(as, Ws, 64, nl0, f0, acc);
  __syncthreads();
  mm_loadw512(Ws, W2 + 12288, tid);
  mm_stage_bf16_512(as, t3b, gb, n, tid);
  __syncthreads();
  mm_acc2(as, Ws, 64, nl0, f0, acc);
#pragma unroll
  for (int j = 0; j < 2; j++) {
    int g = gb + nl0 + j;
    if (g < n) {
#pragma unroll
      for (int jj = 0; jj < 4; jj++) {
        int f = f0 + jj;
        float v = fmaxf(acc[j][jj] + b2[f], 0.f);
        S1[(size_t)g * 64 + f] = v;
        S1b[(size_t)g * 64 + f] = f2bf(v);
      }
    }
  }
}

// ---- phase-E MM + final projection (512 threads) ----
__global__ __launch_bounds__(512)
void k_mm_e(const float* __restrict__ aggSS, const int* __restrict__ cnt_ss,
            const float* __restrict__ W5_l, const float* __restrict__ S1,
            const float* __restrict__ W5_r, const float* __restrict__ b5,
            const float* __restrict__ Wl, const float* __restrict__ bl,
            float* __restrict__ out, int n) {
  __shared__ float Ws[4096];
  __shared__ float as[64 * 68];
  __shared__ float cs[64 * 68];
  const int tid = threadIdx.x;
  const int gb = blockIdx.x * 64;
  const int f0 = (tid & 15) * 4;
  const int nl0 = (tid >> 4) * 2;
  float acc[2][4];
  mm_zero2(acc);
  mm_loadw512(Ws, W5_l, tid);
  mm_stage_f32_512(as, aggSS, cnt_ss, gb, n, tid);
  __syncthreads();
  mm_acc2(as, Ws, 64, nl0, f0, acc);
  __syncthreads();
  mm_loadw512(Ws, W5_r, tid);
  mm_stage_f32_512(cs, S1, nullptr, gb, n, tid);
  __syncthreads();
  mm_acc2(cs, Ws, 64, nl0, f0, acc);
  __syncthreads();
#pragma unroll
  for (int j = 0; j < 2; j++)
#pragma unroll
    for (int jj = 0; jj < 4; jj++)
      as[(nl0 + j) * 68 + f0 + jj] = fmaxf(acc[j][jj] + b5[f0 + jj], 0.f);
  for (int i = tid; i < 512; i += 512) Ws[i] = Wl[i];
  __syncthreads();
  {
    int nl = tid >> 3, o = tid & 7;
    int g = gb + nl;
    if (g < n) {
      float a2 = bl[o];
#pragma unroll 8
      for (int k = 0; k < 64; k++) a2 += as[nl * 68 + k] * Ws[k * 8 + o];
      out[(size_t)g * 8 + o] = a2;
    }
  }
}

// ---------------- Host ----------------

extern "C" void kernel_launch(void* const* d_in, const int* in_sizes, int n_in,
                              void* d_out, int out_size, void* d_ws, size_t ws_size,
                              hipStream_t stream) {
  const float* game_x  = (const float*)d_in[0];
  const float* state_x = (const float*)d_in[1];
  const int*   ei_vv   = (const int*)d_in[2];
  const int*   et_vv   = (const int*)d_in[3];
  const int*   ei_h    = (const int*)d_in[4];
  const float* ew_h    = (const float*)d_in[5];
  const int*   ei_in   = (const int*)d_in[6];
  const int*   ei_ss   = (const int*)d_in[7];
  const float* W1_rel  = (const float*)d_in[8];
  const float* W1_root = (const float*)d_in[9];
  const float* b1      = (const float*)d_in[10];
  const float* W12     = (const float*)d_in[11];
  const float* b12     = (const float*)d_in[12];
  const float* W2      = (const float*)d_in[13];
  const float* b2      = (const float*)d_in[14];
  const float* W3_rel  = (const float*)d_in[15];
  const float* W3_root = (const float*)d_in[16];
  const float* b3      = (const float*)d_in[17];
  const float* W32_l   = (const float*)d_in[18];
  const float* W32_r   = (const float*)d_in[19];
  const float* b32     = (const float*)d_in[20];
  const float* W4_l    = (const float*)d_in[21];
  const float* W4_r    = (const float*)d_in[22];
  const float* b4      = (const float*)d_in[23];
  const float* W42_l   = (const float*)d_in[24];
  const float* W42_r   = (const float*)d_in[25];
  const float* b42     = (const float*)d_in[26];
  const float* W5_l    = (const float*)d_in[27];
  const float* W5_r    = (const float*)d_in[28];
  const float* b5      = (const float*)d_in[29];
  const float* Wl      = (const float*)d_in[30];
  const float* bl      = (const float*)d_in[31];

  // Workspace (4B slots), peak 26.05M slots = 104.2 MiB.
  float* ws = (float*)d_ws;
  int*   cnt_all = (int*)(ws + 0);              // 250K (vv|h|in|ss)
  int*   rs_all  = (int*)(ws + 250000);         // 250K (graph-local values)
  int*   bcnt    = (int*)(ws + 500000);         // 512
  int*   bbase   = (int*)(ws + 500512);         // 512
  int*   cb      = (int*)(ws + 501024);         // 512
  int*   srcs_ss = (int*)(ws + 760000);         // 0.8M  (lives through phase E)
  float4* x_pad  = (float4*)(ws + 1600000);     // 800K
  float4* h1p    = (float4*)(ws + 2400000);
  float4* h2p    = (float4*)(ws + 3200000);
  float4* h3p    = (float4*)(ws + 4000000);
  float4* ra4all = (float4*)(ws + 4800000);     // [NVV][5] float4 = 2.0M slots -> 6.8M
  float* dinvS   = ws + 6800000;                // 50K
  unsigned short* gx16 = (unsigned short*)(ws + 6850000);  // 3.2M slots -> 10.05M
  unsigned* temp_vv    = (unsigned*)(ws + 6850000);        // 1.6M, overlays gx16 front (dead before combine)
  float* aggHw = ws + 10050000;                 // 3.2M
  float* aggHu = ws + 13250000;                 // 3.2M
  float* aggIN = ws + 16450000;                 // 3.2M
  float* S1    = ws + 19650000;                 // 3.2M
  float* S2    = ws + 22850000;                 // 3.2M -> ends 26.05M
  // fill temps overlay agg regions (dead until phase B):
  uint2*    temp_h  = (uint2*)aggHw;
  unsigned* temp_in = (unsigned*)(aggHw + 1600000);
  unsigned* temp_ss = (unsigned*)(aggHw + 2400000);
  // overlays (dead-before-write verified in stream order):
  unsigned short* S2b = (unsigned short*)(ws + 4800000);     // in ra4all region (dead after combine_gx)
  unsigned short* u1b = (unsigned short*)(aggHw + 1600000);  // hop1 aux; aggHw dead after chainC
  float*          aggSS = aggHw + 1600000;                   // phase E (after u1b dead)
  unsigned short* t1b = (unsigned short*)aggHu;              // aggHu dead after chainC
  unsigned short* t2b = (unsigned short*)(aggHu + 1600000);
  unsigned short* t3b = (unsigned short*)aggIN;              // aggIN dead after chainC
  unsigned short* S1b = (unsigned short*)(aggIN + 1600000);  // k_mm_d shadow
  unsigned* payload_vv = (unsigned*)S1;                      // dead after phase A
  unsigned short* u2b  = (unsigned short*)S1;                // hop2 aux; S1 written later by k_mm_d
  int2*     eh         = (int2*)S2;                          // dead after aggB; S2 written by chainC
  int*      srcs_in    = (int*)(S2 + 1600000);

  const int* src_vv = ei_vv;  const int* dst_vv = ei_vv + E_VV;
  const int* src_h  = ei_h;   const int* dst_h  = ei_h + E_H;
  const int* src_in = ei_in;  const int* dst_in = ei_in + E_IN;
  const int* src_ss = ei_ss;  const int* dst_ss = ei_ss + E_SS;

  auto nblk = [](long long n) { return dim3((unsigned)((n + 255) / 256)); };
  const int NB64 = (NSV + 3) / 4;
  const int NB   = (NSV + 63) / 64;
  const int GC   = (ETOT + TC - 1) / TC;

  int* cnt_h  = cnt_all + H_ROW;
  int* cnt_in = cnt_all + IN_ROW;
  int* cnt_ss = cnt_all + SS_ROW;
  int* rs_vv  = rs_all;
  int* rs_h   = rs_all + H_ROW;
  int* rs_in  = rs_all + IN_ROW;
  int* rs_ss  = rs_all + SS_ROW;

  // ---- CSR build (fused) ----
  hipMemsetAsync(bcnt, 0, NBTOT * sizeof(int), stream);
  k_bucket_count<<<GC, 256, 0, stream>>>(dst_vv, dst_h, dst_in, dst_ss, bcnt);
  k_bucket_scan<<<1, 512, 0, stream>>>(bcnt, bbase, cb);
  k_fill_s1_all<<<SB1, 256, 0, stream>>>(src_vv, dst_vv, et_vv, src_h, dst_h, ew_h,
                                         src_in, dst_in, src_ss, dst_ss, cb,
                                         temp_vv, temp_h, temp_in, temp_ss);
  k_fill_s2_all<<<NBTOT, 256, 0, stream>>>(temp_vv, temp_h, temp_in, temp_ss, bbase,
                                           payload_vv, eh, srcs_in, srcs_ss,
                                           rs_all, cnt_all, game_x, x_pad, dinvS);

  // ---- Phase A: v-graph 5-dim ----
  k_vv_pass1<<<nblk(NVV), 256, 0, stream>>>(x_pad, rs_vv, cnt_all, payload_vv, ra4all, h1p);
  k_vv_hop<<<nblk(NVV), 256, 0, stream>>>(h1p, rs_vv, cnt_all, payload_vv, h2p);
  k_vv_hop<<<nblk(NVV), 256, 0, stream>>>(h2p, rs_vv, cnt_all, payload_vv, h3p);
  k_combine_gx<<<dim3((NVV + 31) / 32), 256, 0, stream>>>(x_pad, ra4all, h1p, h2p, h3p,
                                                          W1_rel, W1_root, b1, W12, b12, gx16);

  // ---- Phase B: fused 64-dim bf16 gathers ----
  k_aggB<<<2 * NB64, 256, 0, stream>>>(gx16, rs_h, cnt_h, eh, rs_in, cnt_in, srcs_in,
                                       aggHw, aggHu, aggIN, NB64);

  // ---- Phase C: fused 4-MM chain (512 threads) -> S2 (+ dinv-prescaled bf16 shadow) ----
  k_mm_chainC<<<NB, 512, 0, stream>>>(aggHw, state_x, aggHu, cnt_h, aggIN, cnt_in,
                                      W3_rel, W3_root, b3, W32_l, W32_r, b32,
                                      W4_l, W4_r, b4, W42_l, W42_r, b42,
                                      S2, S2b, dinvS, NSV);

  // ---- Phase D: TAG on s-s (prescaled bf16 hops) + fused quad MM ----
  k_tag64b<<<NB64, 256, 0, stream>>>(S2b, rs_ss, cnt_ss, srcs_ss, dinvS, t1b, u1b, NSV);
  k_tag64b<<<NB64, 256, 0, stream>>>(u1b, rs_ss, cnt_ss, srcs_ss, dinvS, t2b, u2b, NSV);
  k_tag64b<<<NB64, 256, 0, stream>>>(u2b, rs_ss, cnt_ss, srcs_ss, dinvS, t3b, nullptr, NSV);
  k_mm_d<<<NB, 512, 0, stream>>>(S2, t1b, t2b, t3b, W2, b2, S1, S1b, NSV);

  // ---- Phase E: SAGE on s-s + final projection ----
  k_agg64b<<<NB64, 256, 0, stream>>>(S1b, rs_ss, cnt_ss, srcs_ss, aggSS, NSV);
  k_mm_e<<<NB, 512, 0, stream>>>(aggSS, cnt_ss, W5_l, S1, W5_r, b5, Wl, bl, (float*)d_out, NSV);
}

// Round 15
// 675.156 us; speedup vs baseline: 5.6502x; 4.4857x over previous
//
#include <hip/hip_runtime.h>

#define NVV 100000
#define NSV 50000
#define E_VV 1600000
#define E_H  800000
#define E_IN 800000
#define E_SS 800000
#define ETOT 4000000
#define DIN 5
#define H_ROW 100000          // concatenated cnt/rs space: vv|h|in|ss
#define IN_ROW 150000
#define SS_ROW 200000
#define NROWS 250000
#define POS_H  E_VV
#define POS_IN (E_VV + E_H)
#define POS_SS (E_VV + E_H + E_IN)
#define NBUK 196              // vv buckets (dst >> 9)
#define NBUKS 98              // NSV-graph buckets
#define NBTOT 490             // vv|h|in|ss bucket space
#define BUK_H  196
#define BUK_IN 294
#define BUK_SS 392
#define BSHIFT 9
#define T1 4096               // edges per fill-stage-1 block
#define TC 16384              // edges per bucket-count block
#define G1VV 391              // ceil(E_VV/T1)
#define G1S  196              // ceil(E_H/T1)
#define SB1  (G1VV + 3 * G1S) // 979 fused stage-1 blocks

__device__ __forceinline__ unsigned short f2bf(float x) {
  unsigned b = __float_as_uint(x);
  return (unsigned short)((b + 0x7FFFu + ((b >> 16) & 1u)) >> 16);
}
__device__ __forceinline__ float bf2f(unsigned short u) {
  return __uint_as_float(((unsigned)u) << 16);
}

// ====================== CSR build: bucket counts -> bases -> fused binned fills ======================

__global__ __launch_bounds__(256)
void k_bucket_count(const int* __restrict__ d_vv, const int* __restrict__ d_h,
                    const int* __restrict__ d_in, const int* __restrict__ d_ss,
                    int* __restrict__ bcnt) {
  __shared__ int h[NBTOT];
  const int tid = threadIdx.x;
  for (int i = tid; i < NBTOT; i += 256) h[i] = 0;
  __syncthreads();
  const int base = blockIdx.x * TC;
#pragma unroll 4
  for (int k = 0; k < TC / 256; k++) {
    int e = base + k * 256 + tid;
    int bi = -1;
    if (e < E_VV) bi = d_vv[e] >> BSHIFT;
    else if (e < POS_IN) bi = BUK_H + (d_h[e - POS_H] >> BSHIFT);
    else if (e < POS_SS) bi = BUK_IN + (d_in[e - POS_IN] >> BSHIFT);
    else if (e < ETOT) bi = BUK_SS + (d_ss[e - POS_SS] >> BSHIFT);
    if (bi >= 0) atomicAdd(&h[bi], 1);
  }
  __syncthreads();
  for (int i = tid; i < NBTOT; i += 256) if (h[i]) atomicAdd(&bcnt[i], h[i]);
}

__global__ __launch_bounds__(512)
void k_bucket_scan(const int* __restrict__ bcnt, int* __restrict__ bbase, int* __restrict__ cb) {
  __shared__ int sd[512];
  int t = threadIdx.x;
  int v = (t < NBTOT) ? bcnt[t] : 0;
  sd[t] = v; __syncthreads();
  for (int off = 1; off < 512; off <<= 1) {
    int x = (t >= off) ? sd[t - off] : 0;
    __syncthreads();
    sd[t] += x;
    __syncthreads();
  }
  int segstart = (t < BUK_H) ? 0 : (t < BUK_IN) ? BUK_H : (t < BUK_SS) ? BUK_IN : BUK_SS;
  int excl = ((t > 0) ? sd[t - 1] : 0) - ((segstart > 0) ? sd[segstart - 1] : 0);
  if (t < NBTOT) { bbase[t] = excl; cb[t] = excl; }
}

// ---- fused stage 1: all 4 graphs, bucket-grouped binning, coalesced run writes ----
__global__ __launch_bounds__(256)
void k_fill_s1_all(const int* __restrict__ s_vv, const int* __restrict__ d_vv,
                   const int* __restrict__ et,
                   const int* __restrict__ s_h, const int* __restrict__ d_h,
                   const float* __restrict__ ew,
                   const int* __restrict__ s_in, const int* __restrict__ d_in,
                   const int* __restrict__ s_ss, const int* __restrict__ d_ss,
                   int* __restrict__ cb,
                   unsigned* __restrict__ temp_vv, uint2* __restrict__ temp_h,
                   unsigned* __restrict__ temp_in, unsigned* __restrict__ temp_ss) {
  __shared__ int hist[NBUK], lbase[NBUK], run[NBUK], gb[NBUK];
  __shared__ int sc[256];
  __shared__ unsigned stage[T1];
  __shared__ unsigned stageW[T1];
  __shared__ int gpos[T1];
  const int tid = threadIdx.x;
  const int b = blockIdx.x;
  int g, tile;
  if (b < G1VV) { g = 0; tile = b; }
  else if (b < G1VV + G1S) { g = 1; tile = b - G1VV; }
  else if (b < G1VV + 2 * G1S) { g = 2; tile = b - G1VV - G1S; }
  else { g = 3; tile = b - G1VV - 2 * G1S; }
  const int ne = (g == 0) ? E_VV : E_H;
  const int nbuk = (g == 0) ? NBUK : NBUKS;
  const int cboff = (g == 0) ? 0 : (g == 1) ? BUK_H : (g == 2) ? BUK_IN : BUK_SS;
  const int* S = (g == 0) ? s_vv : (g == 1) ? s_h : (g == 2) ? s_in : s_ss;
  const int* D = (g == 0) ? d_vv : (g == 1) ? d_h : (g == 2) ? d_in : d_ss;
  const int base = tile * T1;
  const int nvalid = min(T1, ne - base);
  for (int i = tid; i < nbuk; i += 256) { hist[i] = 0; run[i] = 0; }
  __syncthreads();
  int dv[16]; unsigned pk[16], pkw[16];
#pragma unroll
  for (int k = 0; k < 16; k++) {
    int e = base + k * 256 + tid;
    if (e - base < nvalid) {
      int d = D[e];
      dv[k] = d;
      if (g == 0) pk[k] = (unsigned)(((d & 511) << 19) | (et[e] << 17) | S[e]);
      else pk[k] = (unsigned)(((d & 511) << 17) | S[e]);
      if (g == 1) pkw[k] = (unsigned)__float_as_int(ew[e]);
      atomicAdd(&hist[d >> BSHIFT], 1);
    } else dv[k] = -1;
  }
  __syncthreads();
  int my = (tid < nbuk) ? hist[tid] : 0;
  sc[tid] = my; __syncthreads();
  for (int off = 1; off < 256; off <<= 1) {
    int t = (tid >= off) ? sc[tid - off] : 0;
    __syncthreads();
    sc[tid] += t;
    __syncthreads();
  }
  if (tid < nbuk) {
    lbase[tid] = sc[tid] - my;
    gb[tid] = my ? atomicAdd(&cb[cboff + tid], my) : 0;
  }
  __syncthreads();
#pragma unroll
  for (int k = 0; k < 16; k++) {
    if (dv[k] >= 0) {
      int bu = dv[k] >> BSHIFT;
      int loc = atomicAdd(&run[bu], 1);
      int li = lbase[bu] + loc;
      stage[li] = pk[k];
      if (g == 1) stageW[li] = pkw[k];
      gpos[li] = gb[bu] + loc;
    }
  }
  __syncthreads();
  if (g == 0)      for (int i = tid; i < nvalid; i += 256) temp_vv[gpos[i]] = stage[i];
  else if (g == 1) for (int i = tid; i < nvalid; i += 256) temp_h[gpos[i]] = make_uint2(stage[i], stageW[i]);
  else if (g == 2) for (int i = tid; i < nvalid; i += 256) temp_in[gpos[i]] = stage[i];
  else             for (int i = tid; i < nvalid; i += 256) temp_ss[gpos[i]] = stage[i];
}

// ---- fused stage 2 ----
__global__ __launch_bounds__(256)
void k_fill_s2_all(const unsigned* __restrict__ temp_vv, const uint2* __restrict__ temp_h,
                   const unsigned* __restrict__ temp_in, const unsigned* __restrict__ temp_ss,
                   const int* __restrict__ bbase,
                   unsigned* __restrict__ payload_vv, int2* __restrict__ eh,
                   int* __restrict__ srcs_in, int* __restrict__ srcs_ss,
                   int* __restrict__ rs_all, int* __restrict__ cnt_all,
                   const float* __restrict__ x, float4* __restrict__ xp,
                   float* __restrict__ dinvS) {
  __shared__ int lcnt[512], lpos[512];
  __shared__ int sc[256];
  const int b = blockIdx.x, tid = threadIdx.x;
  int g, lb;
  if (b < BUK_H) { g = 0; lb = b; }
  else if (b < BUK_IN) { g = 1; lb = b - BUK_H; }
  else if (b < BUK_SS) { g = 2; lb = b - BUK_IN; }
  else { g = 3; lb = b - BUK_SS; }
  const int d0 = lb << BSHIFT;
  const int nrows = (g == 0) ? NVV : NSV;
  const int rowbase = (g == 0) ? 0 : (g == 1) ? H_ROW : (g == 2) ? IN_ROW : SS_ROW;
  const int ne = (g == 0) ? E_VV : E_H;
  const int lastb = (g == 0) ? NBUK - 1 : NBUKS - 1;
  const int shift = (g == 0) ? 19 : 17;
  lcnt[tid] = 0; lcnt[tid + 256] = 0;
  __syncthreads();
  const int gstart = bbase[b];
  const int gend = (lb == lastb) ? ne : bbase[b + 1];
  if (g == 1) {
    for (int i = gstart + tid; i < gend; i += 256) atomicAdd(&lcnt[temp_h[i].x >> 17], 1);
  } else {
    const unsigned* tp = (g == 0) ? temp_vv : (g == 2) ? temp_in : temp_ss;
    for (int i = gstart + tid; i < gend; i += 256) atomicAdd(&lcnt[tp[i] >> shift], 1);
  }
  __syncthreads();
  int c0 = lcnt[2 * tid], c1 = lcnt[2 * tid + 1];
  int ps = c0 + c1;
  sc[tid] = ps; __syncthreads();
  for (int off = 1; off < 256; off <<= 1) {
    int x2 = (tid >= off) ? sc[tid - off] : 0;
    __syncthreads();
    sc[tid] += x2;
    __syncthreads();
  }
  int basep = gstart + sc[tid] - ps;
  lpos[2 * tid] = basep;
  lpos[2 * tid + 1] = basep + c0;
  __syncthreads();
  for (int d = tid; d < 512; d += 256) {
    int gd = d0 + d;
    if (gd < nrows) {
      rs_all[rowbase + gd] = lpos[d];
      cnt_all[rowbase + gd] = lcnt[d];
      if (g == 0) {
        float dc = (float)lcnt[d];
        float di = dc > 0.f ? rsqrtf(dc) : 0.f;
        const float* xr = x + (size_t)gd * 5;
        xp[gd * 2]     = make_float4(xr[0], xr[1], xr[2], xr[3]);
        xp[gd * 2 + 1] = make_float4(xr[4], di, 0.f, 0.f);
      } else if (g == 3) {
        float dc = (float)lcnt[d];
        dinvS[gd] = dc > 0.f ? rsqrtf(dc) : 0.f;
      }
    }
  }
  __syncthreads();
  if (g == 0) {
    for (int i = gstart + tid; i < gend; i += 256) {
      unsigned en = temp_vv[i];
      int pos = atomicAdd(&lpos[en >> 19], 1);
      payload_vv[pos] = en & 0x7FFFFu;
    }
  } else if (g == 1) {
    for (int i = gstart + tid; i < gend; i += 256) {
      uint2 en = temp_h[i];
      int pos = atomicAdd(&lpos[en.x >> 17], 1);
      eh[pos] = make_int2((int)(en.x & 0x1FFFFu), (int)en.y);
    }
  } else if (g == 2) {
    for (int i = gstart + tid; i < gend; i += 256) {
      unsigned en = temp_in[i];
      int pos = atomicAdd(&lpos[en >> 17], 1);
      srcs_in[pos] = (int)(en & 0x1FFFFu);
    }
  } else {
    for (int i = gstart + tid; i < gend; i += 256) {
      unsigned en = temp_ss[i];
      int pos = atomicAdd(&lpos[en >> 17], 1);
      srcs_ss[pos] = (int)(en & 0x1FFFFu);
    }
  }
}

// ====================== Phase A: v-graph (5-dim, padded rows) ======================

__global__ __launch_bounds__(256)
void k_vv_pass1(const float4* __restrict__ xp,
                const int* __restrict__ rowstart, const int* __restrict__ cnt,
                const unsigned* __restrict__ payload,
                float4* __restrict__ ra4all, float4* __restrict__ h1p) {
  int d = blockIdx.x * 256 + threadIdx.x;
  if (d >= NVV) return;
  int rs = rowstart[d], c = cnt[d];
  float a0[5] = {0,0,0,0,0}, a1[5] = {0,0,0,0,0}, a2[5] = {0,0,0,0,0}, h[5] = {0,0,0,0,0};
  float c0 = 0.f, c1 = 0.f, c2 = 0.f;
  int j = 0;
  for (; j + 2 <= c; j += 2) {
    unsigned pA = payload[rs + j], pB = payload[rs + j + 1];
    int sA = pA & 0x1FFFF, rA = pA >> 17;
    int sB = pB & 0x1FFFF, rB = pB >> 17;
    float4 xA0 = xp[sA * 2], xA1 = xp[sA * 2 + 1];
    float4 xB0 = xp[sB * 2], xB1 = xp[sB * 2 + 1];
    float xsA[5] = {xA0.x, xA0.y, xA0.z, xA0.w, xA1.x};
    float xsB[5] = {xB0.x, xB0.y, xB0.z, xB0.w, xB1.x};
    float wA = xA1.y, wB = xB1.y;
    float mA0 = (rA == 0) ? 1.f : 0.f, mA1 = (rA == 1) ? 1.f : 0.f, mA2 = (rA == 2) ? 1.f : 0.f;
    float mB0 = (rB == 0) ? 1.f : 0.f, mB1 = (rB == 1) ? 1.f : 0.f, mB2 = (rB == 2) ? 1.f : 0.f;
    c0 += mA0 + mB0; c1 += mA1 + mB1; c2 += mA2 + mB2;
#pragma unroll
    for (int k = 0; k < 5; k++) {
      h[k] += wA * xsA[k] + wB * xsB[k];
      a0[k] += mA0 * xsA[k] + mB0 * xsB[k];
      a1[k] += mA1 * xsA[k] + mB1 * xsB[k];
      a2[k] += mA2 * xsA[k] + mB2 * xsB[k];
    }
  }
  for (; j < c; j++) {
    unsigned p = payload[rs + j];
    int s = p & 0x1FFFF, r = p >> 17;
    float4 x0 = xp[s * 2], x1 = xp[s * 2 + 1];
    float xs[5] = {x0.x, x0.y, x0.z, x0.w, x1.x};
    float wsc = x1.y;
    float m0 = (r == 0) ? 1.f : 0.f, m1 = (r == 1) ? 1.f : 0.f, m2 = (r == 2) ? 1.f : 0.f;
    c0 += m0; c1 += m1; c2 += m2;
#pragma unroll
    for (int k = 0; k < 5; k++) {
      h[k] += wsc * xs[k];
      a0[k] += m0 * xs[k]; a1[k] += m1 * xs[k]; a2[k] += m2 * xs[k];
    }
  }
  float dv = xp[d * 2 + 1].y;
  float4* ra4 = ra4all + d * 5;
  ra4[0] = make_float4(a0[0], a0[1], a0[2], a0[3]);
  ra4[1] = make_float4(a0[4], a1[0], a1[1], a1[2]);
  ra4[2] = make_float4(a1[3], a1[4], a2[0], a2[1]);
  ra4[3] = make_float4(a2[2], a2[3], a2[4], c0);
  ra4[4] = make_float4(c1, c2, 0.f, 0.f);
  h1p[d * 2]     = make_float4(dv * h[0], dv * h[1], dv * h[2], dv * h[3]);
  h1p[d * 2 + 1] = make_float4(dv * h[4], dv, 0.f, 0.f);
}

__global__ __launch_bounds__(256)
void k_vv_hop(const float4* __restrict__ hinp,
              const int* __restrict__ rowstart, const int* __restrict__ cnt,
              const unsigned* __restrict__ payload, float4* __restrict__ houtp) {
  int d = blockIdx.x * 256 + threadIdx.x;
  if (d >= NVV) return;
  int rs = rowstart[d], c = cnt[d];
  float h[5] = {0,0,0,0,0};
  int j = 0;
  for (; j + 4 <= c; j += 4) {
    unsigned p0 = payload[rs + j], p1 = payload[rs + j + 1];
    unsigned p2 = payload[rs + j + 2], p3 = payload[rs + j + 3];
    int s0 = p0 & 0x1FFFF, s1 = p1 & 0x1FFFF, s2 = p2 & 0x1FFFF, s3 = p3 & 0x1FFFF;
    float4 a0 = hinp[s0 * 2], b0 = hinp[s0 * 2 + 1];
    float4 a1 = hinp[s1 * 2], b1 = hinp[s1 * 2 + 1];
    float4 a2 = hinp[s2 * 2], b2 = hinp[s2 * 2 + 1];
    float4 a3 = hinp[s3 * 2], b3 = hinp[s3 * 2 + 1];
    float w0 = b0.y, w1 = b1.y, w2 = b2.y, w3 = b3.y;
    h[0] += w0 * a0.x + w1 * a1.x + w2 * a2.x + w3 * a3.x;
    h[1] += w0 * a0.y + w1 * a1.y + w2 * a2.y + w3 * a3.y;
    h[2] += w0 * a0.z + w1 * a1.z + w2 * a2.z + w3 * a3.z;
    h[3] += w0 * a0.w + w1 * a1.w + w2 * a2.w + w3 * a3.w;
    h[4] += w0 * b0.x + w1 * b1.x + w2 * b2.x + w3 * b3.x;
  }
  for (; j < c; j++) {
    int s = payload[rs + j] & 0x1FFFF;
    float4 x0 = hinp[s * 2], x1 = hinp[s * 2 + 1];
    float wsc = x1.y;
    h[0] += wsc * x0.x; h[1] += wsc * x0.y; h[2] += wsc * x0.z; h[3] += wsc * x0.w;
    h[4] += wsc * x1.x;
  }
  float dv = hinp[d * 2 + 1].y;
  houtp[d * 2]     = make_float4(dv * h[0], dv * h[1], dv * h[2], dv * h[3]);
  houtp[d * 2 + 1] = make_float4(dv * h[4], dv, 0.f, 0.f);
}

// 8 nodes/thread, Ws column in 35 VGPRs, float4 relall loads.
__global__ __launch_bounds__(256)
void k_combine_gx(const float4* __restrict__ xp,
                  const float4* __restrict__ ra4all,
                  const float4* __restrict__ h1p, const float4* __restrict__ h2p,
                  const float4* __restrict__ h3p,
                  const float* __restrict__ W1_rel, const float* __restrict__ W1_root,
                  const float* __restrict__ b1,
                  const float* __restrict__ W12, const float* __restrict__ b12,
                  unsigned short* __restrict__ gx16) {
  __shared__ float Ws[7 * 320];
  __shared__ float bs[64];
  int tid = threadIdx.x;
  for (int i = tid; i < 320; i += 256) {
    Ws[i]        = W1_root[i] + W12[i];
    Ws[320 + i]  = W1_rel[i];
    Ws[640 + i]  = W1_rel[320 + i];
    Ws[960 + i]  = W1_rel[640 + i];
    Ws[1280 + i] = W12[320 + i];
    Ws[1600 + i] = W12[640 + i];
    Ws[1920 + i] = W12[960 + i];
  }
  if (tid < 64) bs[tid] = b1[tid] + b12[tid];
  __syncthreads();
  const int f = tid & 63;
  const int grp = tid >> 6;
  float wcol[35];
#pragma unroll
  for (int t = 0; t < 35; t++) wcol[t] = Ws[t * 64 + f];
  const float bias = bs[f];
  const int v0 = blockIdx.x * 32 + grp * 8;
  for (int n = 0; n < 8; n++) {
    int v = v0 + n;
    if (v >= NVV) return;
    float in[35];
    {
      float4 x0 = xp[v * 2], x1 = xp[v * 2 + 1];
      in[0] = x0.x; in[1] = x0.y; in[2] = x0.z; in[3] = x0.w; in[4] = x1.x;
    }
    {
      const float4* ra = ra4all + v * 5;
      float4 r0 = ra[0], r1 = ra[1], r2 = ra[2], r3 = ra[3], r4 = ra[4];
      float i0 = 1.0f / fmaxf(r3.w, 1.0f);
      float i1 = 1.0f / fmaxf(r4.x, 1.0f);
      float i2 = 1.0f / fmaxf(r4.y, 1.0f);
      in[5]  = r0.x * i0; in[6]  = r0.y * i0; in[7]  = r0.z * i0; in[8]  = r0.w * i0; in[9]  = r1.x * i0;
      in[10] = r1.y * i1; in[11] = r1.z * i1; in[12] = r1.w * i1; in[13] = r2.x * i1; in[14] = r2.y * i1;
      in[15] = r2.z * i2; in[16] = r2.w * i2; in[17] = r3.x * i2; in[18] = r3.y * i2; in[19] = r3.z * i2;
    }
    {
      float4 a = h1p[v * 2], b = h1p[v * 2 + 1];
      in[20] = a.x; in[21] = a.y; in[22] = a.z; in[23] = a.w; in[24] = b.x;
      a = h2p[v * 2]; b = h2p[v * 2 + 1];
      in[25] = a.x; in[26] = a.y; in[27] = a.z; in[28] = a.w; in[29] = b.x;
      a = h3p[v * 2]; b = h3p[v * 2 + 1];
      in[30] = a.x; in[31] = a.y; in[32] = a.z; in[33] = a.w; in[34] = b.x;
    }
    float acc = bias;
#pragma unroll
    for (int t = 0; t < 35; t++) acc += in[t] * wcol[t];
    gx16[v * 64 + f] = f2bf(acc);
  }
}

// ================= 64-dim CSR gathers (wave per dst, lane=feature, 8-way MLP) =================

__global__ __launch_bounds__(256)
void k_aggB(const unsigned short* __restrict__ X16,
            const int* __restrict__ rs_h, const int* __restrict__ cnt_h,
            const int2* __restrict__ eh,
            const int* __restrict__ rs_in, const int* __restrict__ cnt_in,
            const int* __restrict__ srcs_in,
            float* __restrict__ outw, float* __restrict__ outu, float* __restrict__ outIN,
            int nb64) {
  int bb = blockIdx.x;
  int lane = threadIdx.x & 63;
  if (bb < nb64) {
    int wid = bb * 4 + (threadIdx.x >> 6);
    if (wid >= NSV) return;
    int rs = rs_h[wid], c = cnt_h[wid];
    float aw = 0.f, au = 0.f;
    int j = 0;
    for (; j + 8 <= c; j += 8) {
      int2 p0 = eh[rs + j],     p1 = eh[rs + j + 1], p2 = eh[rs + j + 2], p3 = eh[rs + j + 3];
      int2 p4 = eh[rs + j + 4], p5 = eh[rs + j + 5], p6 = eh[rs + j + 6], p7 = eh[rs + j + 7];
      float v0 = bf2f(X16[p0.x * 64 + lane]);
      float v1 = bf2f(X16[p1.x * 64 + lane]);
      float v2 = bf2f(X16[p2.x * 64 + lane]);
      float v3 = bf2f(X16[p3.x * 64 + lane]);
      float v4 = bf2f(X16[p4.x * 64 + lane]);
      float v5 = bf2f(X16[p5.x * 64 + lane]);
      float v6 = bf2f(X16[p6.x * 64 + lane]);
      float v7 = bf2f(X16[p7.x * 64 + lane]);
      au += ((v0 + v1) + (v2 + v3)) + ((v4 + v5) + (v6 + v7));
      aw += __int_as_float(p0.y) * v0 + __int_as_float(p1.y) * v1
          + __int_as_float(p2.y) * v2 + __int_as_float(p3.y) * v3
          + __int_as_float(p4.y) * v4 + __int_as_float(p5.y) * v5
          + __int_as_float(p6.y) * v6 + __int_as_float(p7.y) * v7;
    }
    for (; j < c; j++) {
      int2 p = eh[rs + j];
      float v = bf2f(X16[p.x * 64 + lane]);
      au += v; aw += __int_as_float(p.y) * v;
    }
    outw[wid * 64 + lane] = aw;
    outu[wid * 64 + lane] = au;
  } else {
    int wid = (bb - nb64) * 4 + (threadIdx.x >> 6);
    if (wid >= NSV) return;
    int rs = rs_in[wid], c = cnt_in[wid];
    float a = 0.f;
    int j = 0;
    for (; j + 8 <= c; j += 8) {
      int s0 = srcs_in[rs + j],     s1 = srcs_in[rs + j + 1], s2 = srcs_in[rs + j + 2], s3 = srcs_in[rs + j + 3];
      int s4 = srcs_in[rs + j + 4], s5 = srcs_in[rs + j + 5], s6 = srcs_in[rs + j + 6], s7 = srcs_in[rs + j + 7];
      float v0 = bf2f(X16[s0 * 64 + lane]);
      float v1 = bf2f(X16[s1 * 64 + lane]);
      float v2 = bf2f(X16[s2 * 64 + lane]);
      float v3 = bf2f(X16[s3 * 64 + lane]);
      float v4 = bf2f(X16[s4 * 64 + lane]);
      float v5 = bf2f(X16[s5 * 64 + lane]);
      float v6 = bf2f(X16[s6 * 64 + lane]);
      float v7 = bf2f(X16[s7 * 64 + lane]);
      a += ((v0 + v1) + (v2 + v3)) + ((v4 + v5) + (v6 + v7));
    }
    for (; j < c; j++) a += bf2f(X16[srcs_in[rs + j] * 64 + lane]);
    outIN[wid * 64 + lane] = a;
  }
}

__global__ __launch_bounds__(256)
void k_agg64b(const unsigned short* __restrict__ X16,
              const int* __restrict__ rowstart, const int* __restrict__ cnt,
              const int* __restrict__ srcs, float* __restrict__ out, int n) {
  int wid = blockIdx.x * 4 + (threadIdx.x >> 6);
  if (wid >= n) return;
  int lane = threadIdx.x & 63;
  int rs = rowstart[wid], c = cnt[wid];
  float a = 0.f;
  int j = 0;
  for (; j + 8 <= c; j += 8) {
    int s0 = srcs[rs + j],     s1 = srcs[rs + j + 1], s2 = srcs[rs + j + 2], s3 = srcs[rs + j + 3];
    int s4 = srcs[rs + j + 4], s5 = srcs[rs + j + 5], s6 = srcs[rs + j + 6], s7 = srcs[rs + j + 7];
    float v0 = bf2f(X16[s0 * 64 + lane]);
    float v1 = bf2f(X16[s1 * 64 + lane]);
    float v2 = bf2f(X16[s2 * 64 + lane]);
    float v3 = bf2f(X16[s3 * 64 + lane]);
    float v4 = bf2f(X16[s4 * 64 + lane]);
    float v5 = bf2f(X16[s5 * 64 + lane]);
    float v6 = bf2f(X16[s6 * 64 + lane]);
    float v7 = bf2f(X16[s7 * 64 + lane]);
    a += ((v0 + v1) + (v2 + v3)) + ((v4 + v5) + (v6 + v7));
  }
  for (; j < c; j++) a += bf2f(X16[srcs[rs + j] * 64 + lane]);
  out[wid * 64 + lane] = a;
}

// prescaled TAG hop: U = dinv ⊙ t (bf16). t_out = dinv[d]*Σ U[s]; u_out = dinv[d]*t_out.
__global__ __launch_bounds__(256)
void k_tag64b(const unsigned short* __restrict__ U16,
              const int* __restrict__ rowstart, const int* __restrict__ cnt,
              const int* __restrict__ srcs, const float* __restrict__ dinv,
              unsigned short* __restrict__ t_out, unsigned short* __restrict__ u_out, int n) {
  int wid = blockIdx.x * 4 + (threadIdx.x >> 6);
  if (wid >= n) return;
  int lane = threadIdx.x & 63;
  int rs = rowstart[wid], c = cnt[wid];
  float a = 0.f;
  int j = 0;
  for (; j + 8 <= c; j += 8) {
    int s0 = srcs[rs + j],     s1 = srcs[rs + j + 1], s2 = srcs[rs + j + 2], s3 = srcs[rs + j + 3];
    int s4 = srcs[rs + j + 4], s5 = srcs[rs + j + 5], s6 = srcs[rs + j + 6], s7 = srcs[rs + j + 7];
    float v0 = bf2f(U16[s0 * 64 + lane]);
    float v1 = bf2f(U16[s1 * 64 + lane]);
    float v2 = bf2f(U16[s2 * 64 + lane]);
    float v3 = bf2f(U16[s3 * 64 + lane]);
    float v4 = bf2f(U16[s4 * 64 + lane]);
    float v5 = bf2f(U16[s5 * 64 + lane]);
    float v6 = bf2f(U16[s6 * 64 + lane]);
    float v7 = bf2f(U16[s7 * 64 + lane]);
    a += ((v0 + v1) + (v2 + v3)) + ((v4 + v5) + (v6 + v7));
  }
  for (; j < c; j++) a += bf2f(U16[srcs[rs + j] * 64 + lane]);
  float dv = dinv[wid];
  float t = dv * a;
  t_out[wid * 64 + lane] = f2bf(t);
  if (u_out) u_out[wid * 64 + lane] = f2bf(dv * t);
}

// ====================== Fused MM building blocks (256 threads, 4 nodes x 4 feats) ======================
// NOTE (r12-r14): 512-thread variants of these kernels produced ~2-4 GB of
// phantom FETCH/WRITE traffic (scratch-like) at ANY launch-bounds setting
// (VGPR 32/40/128 all pathological) -> 1.5 ms/launch. The 256-thread forms
// below are the round-11-verified versions (676 us total). Do not re-widen.

__device__ __forceinline__ void mm_zero(float acc[4][4]) {
#pragma unroll
  for (int j = 0; j < 4; j++)
#pragma unroll
    for (int jj = 0; jj < 4; jj++) acc[j][jj] = 0.f;
}

__device__ __forceinline__ void mm_acc(const float* sA, const float* sW, int K,
                                       int nl0, int f0, float acc[4][4]) {
  for (int k = 0; k < K; k++) {
    float4 w = *(const float4*)(&sW[k * 64 + f0]);
#pragma unroll
    for (int j = 0; j < 4; j++) {
      float a = sA[(nl0 + j) * 68 + k];
      acc[j][0] += a * w.x; acc[j][1] += a * w.y; acc[j][2] += a * w.z; acc[j][3] += a * w.w;
    }
  }
}

__device__ __forceinline__ void mm_loadw(float* Ws, const float* W, int tid) {
  const float4* w4 = (const float4*)W;
  float4* s4 = (float4*)Ws;
  for (int i = tid; i < 1024; i += 256) s4[i] = w4[i];
}

__device__ __forceinline__ void mm_stage_f32(float* as, const float* A, const int* cntA,
                                             int gb, int n, int tid) {
  for (int i = tid; i < 1024; i += 256) {
    int nl = i >> 4, k4 = i & 15;
    int g = gb + nl;
    float4 v = make_float4(0.f, 0.f, 0.f, 0.f);
    if (g < n) {
      v = ((const float4*)A)[g * 16 + k4];
      if (cntA) {
        float sc = 1.0f / fmaxf((float)cntA[g], 1.0f);
        v.x *= sc; v.y *= sc; v.z *= sc; v.w *= sc;
      }
    }
    *(float4*)(&as[nl * 68 + k4 * 4]) = v;
  }
}

__device__ __forceinline__ void mm_stage_bf16(float* as, const unsigned short* A,
                                              int gb, int n, int tid) {
  for (int i = tid; i < 1024; i += 256) {
    int nl = i >> 4, k4 = i & 15;
    int g = gb + nl;
    float4 v = make_float4(0.f, 0.f, 0.f, 0.f);
    if (g < n) {
      uint2 u = ((const uint2*)(A + (size_t)g * 64))[k4];
      v.x = bf2f((unsigned short)(u.x & 0xFFFF));
      v.y = bf2f((unsigned short)(u.x >> 16));
      v.z = bf2f((unsigned short)(u.y & 0xFFFF));
      v.w = bf2f((unsigned short)(u.y >> 16));
    }
    *(float4*)(&as[nl * 68 + k4 * 4]) = v;
  }
}

// ---- phase-C chain: S2 = relu(aggIN'@W42_l + relu(aggIN'@W4_l + relu(aggHu'@W32_l +
//      relu(aggHw@W3_rel + sx@W3_root + b3)@W32_r + b32)@W4_r + b4)@W42_r + b42) ----
__global__ __launch_bounds__(256)
void k_mm_chainC(const float* __restrict__ aggHw, const float* __restrict__ state_x,
                 const float* __restrict__ aggHu, const int* __restrict__ cnt_h,
                 const float* __restrict__ aggIN, const int* __restrict__ cnt_in,
                 const float* __restrict__ W3_rel, const float* __restrict__ W3_root,
                 const float* __restrict__ b3,
                 const float* __restrict__ W32_l, const float* __restrict__ W32_r,
                 const float* __restrict__ b32,
                 const float* __restrict__ W4_l, const float* __restrict__ W4_r,
                 const float* __restrict__ b4,
                 const float* __restrict__ W42_l, const float* __restrict__ W42_r,
                 const float* __restrict__ b42,
                 float* __restrict__ S2out, unsigned short* __restrict__ S2b,
                 const float* __restrict__ dinvS, int n) {
  __shared__ float Ws[4096];
  __shared__ float as[64 * 68];
  __shared__ float cs[64 * 68];
  const int tid = threadIdx.x;
  const int gb = blockIdx.x * 64;
  const int lane = tid & 63;
  const int fq = lane & 15, nq = lane >> 4;
  const int f0 = fq * 4;
  const int nl0 = (tid >> 6) * 16 + nq * 4;
  float acc[4][4];

  // --- C1: aggHw@W3_rel + state_x@W3_root + b3, relu -> cs ---
  mm_loadw(Ws, W3_rel, tid);
  mm_stage_f32(as, aggHw, nullptr, gb, n, tid);
  __syncthreads();
  mm_zero(acc);
  mm_acc(as, Ws, 64, nl0, f0, acc);
  __syncthreads();
  for (int i = tid; i < 320; i += 256) {
    int nl = i / 5, k = i - nl * 5;
    int g = gb + nl;
    as[nl * 68 + k] = (g < n) ? state_x[(size_t)g * 5 + k] : 0.f;
  }
  for (int i = tid; i < 320; i += 256) Ws[i] = W3_root[i];
  __syncthreads();
  mm_acc(as, Ws, 5, nl0, f0, acc);
#pragma unroll
  for (int j = 0; j < 4; j++)
#pragma unroll
    for (int jj = 0; jj < 4; jj++)
      cs[(nl0 + j) * 68 + f0 + jj] = fmaxf(acc[j][jj] + b3[f0 + jj], 0.f);
  __syncthreads();

  // --- C2: aggHu'@W32_l + cs@W32_r + b32, relu -> cs ---
  mm_loadw(Ws, W32_l, tid);
  mm_stage_f32(as, aggHu, cnt_h, gb, n, tid);
  __syncthreads();
  mm_zero(acc);
  mm_acc(as, Ws, 64, nl0, f0, acc);
  __syncthreads();
  mm_loadw(Ws, W32_r, tid);
  __syncthreads();
  mm_acc(cs, Ws, 64, nl0, f0, acc);
  __syncthreads();
#pragma unroll
  for (int j = 0; j < 4; j++)
#pragma unroll
    for (int jj = 0; jj < 4; jj++)
      cs[(nl0 + j) * 68 + f0 + jj] = fmaxf(acc[j][jj] + b32[f0 + jj], 0.f);
  __syncthreads();

  // --- C3: aggIN'@W4_l + cs@W4_r + b4, relu -> cs ---
  mm_loadw(Ws, W4_l, tid);
  mm_stage_f32(as, aggIN, cnt_in, gb, n, tid);
  __syncthreads();
  mm_zero(acc);
  mm_acc(as, Ws, 64, nl0, f0, acc);
  __syncthreads();
  mm_loadw(Ws, W4_r, tid);
  __syncthreads();
  mm_acc(cs, Ws, 64, nl0, f0, acc);
  __syncthreads();
#pragma unroll
  for (int j = 0; j < 4; j++)
#pragma unroll
    for (int jj = 0; jj < 4; jj++)
      cs[(nl0 + j) * 68 + f0 + jj] = fmaxf(acc[j][jj] + b4[f0 + jj], 0.f);
  __syncthreads();

  // --- C4: aggIN'@W42_l + cs@W42_r + b42, relu -> S2 + S2b(dinv-scaled) ---
  mm_loadw(Ws, W42_l, tid);
  mm_stage_f32(as, aggIN, cnt_in, gb, n, tid);
  __syncthreads();
  mm_zero(acc);
  mm_acc(as, Ws, 64, nl0, f0, acc);
  __syncthreads();
  mm_loadw(Ws, W42_r, tid);
  __syncthreads();
  mm_acc(cs, Ws, 64, nl0, f0, acc);
#pragma unroll
  for (int j = 0; j < 4; j++) {
    int g = gb + nl0 + j;
    if (g < n) {
      float osc = dinvS[g];
#pragma unroll
      for (int jj = 0; jj < 4; jj++) {
        int f = f0 + jj;
        float v = fmaxf(acc[j][jj] + b42[f], 0.f);
        S2out[(size_t)g * 64 + f] = v;
        S2b[(size_t)g * 64 + f] = f2bf(v * osc);
      }
    }
  }
}

// ---- phase-D quad MM: S1 = relu(S2@W2_0 + t1@W2_1 + t2@W2_2 + t3@W2_3 + b2); S1b = bf16 ----
__global__ __launch_bounds__(256)
void k_mm_d(const float* __restrict__ S2, const unsigned short* __restrict__ t1b,
            const unsigned short* __restrict__ t2b, const unsigned short* __restrict__ t3b,
            const float* __restrict__ W2, const float* __restrict__ b2,
            float* __restrict__ S1, unsigned short* __restrict__ S1b, int n) {
  __shared__ float Ws[4096];
  __shared__ float as[64 * 68];
  const int tid = threadIdx.x;
  const int gb = blockIdx.x * 64;
  const int lane = tid & 63;
  const int fq = lane & 15, nq = lane >> 4;
  const int f0 = fq * 4;
  const int nl0 = (tid >> 6) * 16 + nq * 4;
  float acc[4][4];
  mm_zero(acc);
  // op 0: S2 (f32)
  mm_loadw(Ws, W2, tid);
  mm_stage_f32(as, S2, nullptr, gb, n, tid);
  __syncthreads();
  mm_acc(as, Ws, 64, nl0, f0, acc);
  __syncthreads();
  // op 1: t1 (bf16)
  mm_loadw(Ws, W2 + 4096, tid);
  mm_stage_bf16(as, t1b, gb, n, tid);
  __syncthreads();
  mm_acc(as, Ws, 64, nl0, f0, acc);
  __syncthreads();
  // op 2: t2 (bf16)
  mm_loadw(Ws, W2 + 8192, tid);
  mm_stage_bf16(as, t2b, gb, n, tid);
  __syncthreads();
  mm_acc(as, Ws, 64, nl0, f0, acc);
  __syncthreads();
  // op 3: t3 (bf16)
  mm_loadw(Ws, W2 + 12288, tid);
  mm_stage_bf16(as, t3b, gb, n, tid);
  __syncthreads();
  mm_acc(as, Ws, 64, nl0, f0, acc);
#pragma unroll
  for (int j = 0; j < 4; j++) {
    int g = gb + nl0 + j;
    if (g < n) {
#pragma unroll
      for (int jj = 0; jj < 4; jj++) {
        int f = f0 + jj;
        float v = fmaxf(acc[j][jj] + b2[f], 0.f);
        S1[(size_t)g * 64 + f] = v;
        S1b[(size_t)g * 64 + f] = f2bf(v);
      }
    }
  }
}

// ---- phase-E MM + final projection: out = relu(aggSS'@W5_l + S1@W5_r + b5) @ Wl + bl ----
__global__ __launch_bounds__(256)
void k_mm_e(const float* __restrict__ aggSS, const int* __restrict__ cnt_ss,
            const float* __restrict__ W5_l, const float* __restrict__ S1,
            const float* __restrict__ W5_r, const float* __restrict__ b5,
            const float* __restrict__ Wl, const float* __restrict__ bl,
            float* __restrict__ out, int n) {
  __shared__ float Ws[4096];
  __shared__ float as[64 * 68];
  __shared__ float cs[64 * 68];
  const int tid = threadIdx.x;
  const int gb = blockIdx.x * 64;
  const int lane = tid & 63;
  const int fq = lane & 15, nq = lane >> 4;
  const int f0 = fq * 4;
  const int nl0 = (tid >> 6) * 16 + nq * 4;
  float acc[4][4];
  mm_zero(acc);
  mm_loadw(Ws, W5_l, tid);
  mm_stage_f32(as, aggSS, cnt_ss, gb, n, tid);
  __syncthreads();
  mm_acc(as, Ws, 64, nl0, f0, acc);
  __syncthreads();
  mm_loadw(Ws, W5_r, tid);
  mm_stage_f32(cs, S1, nullptr, gb, n, tid);
  __syncthreads();
  mm_acc(cs, Ws, 64, nl0, f0, acc);
  // stage relu'd result into as, then project 64->8
  __syncthreads();
#pragma unroll
  for (int j = 0; j < 4; j++)
#pragma unroll
    for (int jj = 0; jj < 4; jj++)
      as[(nl0 + j) * 68 + f0 + jj] = fmaxf(acc[j][jj] + b5[f0 + jj], 0.f);
  for (int i = tid; i < 512; i += 256) Ws[i] = Wl[i];
  __syncthreads();
#pragma unroll
  for (int q = 0; q < 2; q++) {
    int idx = tid * 2 + q;
    int nl = idx >> 3, o = idx & 7;
    int g = gb + nl;
    if (g < n) {
      float a2 = bl[o];
#pragma unroll 8
      for (int k = 0; k < 64; k++) a2 += as[nl * 68 + k] * Ws[k * 8 + o];
      out[(size_t)g * 8 + o] = a2;
    }
  }
}

// ---------------- Host ----------------

extern "C" void kernel_launch(void* const* d_in, const int* in_sizes, int n_in,
                              void* d_out, int out_size, void* d_ws, size_t ws_size,
                              hipStream_t stream) {
  const float* game_x  = (const float*)d_in[0];
  const float* state_x = (const float*)d_in[1];
  const int*   ei_vv   = (const int*)d_in[2];
  const int*   et_vv   = (const int*)d_in[3];
  const int*   ei_h    = (const int*)d_in[4];
  const float* ew_h    = (const float*)d_in[5];
  const int*   ei_in   = (const int*)d_in[6];
  const int*   ei_ss   = (const int*)d_in[7];
  const float* W1_rel  = (const float*)d_in[8];
  const float* W1_root = (const float*)d_in[9];
  const float* b1      = (const float*)d_in[10];
  const float* W12     = (const float*)d_in[11];
  const float* b12     = (const float*)d_in[12];
  const float* W2      = (const float*)d_in[13];
  const float* b2      = (const float*)d_in[14];
  const float* W3_rel  = (const float*)d_in[15];
  const float* W3_root = (const float*)d_in[16];
  const float* b3      = (const float*)d_in[17];
  const float* W32_l   = (const float*)d_in[18];
  const float* W32_r   = (const float*)d_in[19];
  const float* b32     = (const float*)d_in[20];
  const float* W4_l    = (const float*)d_in[21];
  const float* W4_r    = (const float*)d_in[22];
  const float* b4      = (const float*)d_in[23];
  const float* W42_l   = (const float*)d_in[24];
  const float* W42_r   = (const float*)d_in[25];
  const float* b42     = (const float*)d_in[26];
  const float* W5_l    = (const float*)d_in[27];
  const float* W5_r    = (const float*)d_in[28];
  const float* b5      = (const float*)d_in[29];
  const float* Wl      = (const float*)d_in[30];
  const float* bl      = (const float*)d_in[31];

  // Workspace (4B slots), peak 26.05M slots = 104.2 MiB.
  float* ws = (float*)d_ws;
  int*   cnt_all = (int*)(ws + 0);              // 250K (vv|h|in|ss)
  int*   rs_all  = (int*)(ws + 250000);         // 250K (graph-local values)
  int*   bcnt    = (int*)(ws + 500000);         // 512
  int*   bbase   = (int*)(ws + 500512);         // 512
  int*   cb      = (int*)(ws + 501024);         // 512
  int*   srcs_ss = (int*)(ws + 760000);         // 0.8M  (lives through phase E)
  float4* x_pad  = (float4*)(ws + 1600000);     // 800K
  float4* h1p    = (float4*)(ws + 2400000);
  float4* h2p    = (float4*)(ws + 3200000);
  float4* h3p    = (float4*)(ws + 4000000);
  float4* ra4all = (float4*)(ws + 4800000);     // [NVV][5] float4 = 2.0M slots -> 6.8M
  float* dinvS   = ws + 6800000;                // 50K
  unsigned short* gx16 = (unsigned short*)(ws + 6850000);  // 3.2M slots -> 10.05M
  unsigned* temp_vv    = (unsigned*)(ws + 6850000);        // 1.6M, overlays gx16 front (dead before combine)
  float* aggHw = ws + 10050000;                 // 3.2M
  float* aggHu = ws + 13250000;                 // 3.2M
  float* aggIN = ws + 16450000;                 // 3.2M
  float* S1    = ws + 19650000;                 // 3.2M
  float* S2    = ws + 22850000;                 // 3.2M -> ends 26.05M
  // fill temps overlay agg regions (dead until phase B):
  uint2*    temp_h  = (uint2*)aggHw;
  unsigned* temp_in = (unsigned*)(aggHw + 1600000);
  unsigned* temp_ss = (unsigned*)(aggHw + 2400000);
  // overlays (dead-before-write verified in stream order):
  unsigned short* S2b = (unsigned short*)(ws + 4800000);     // in ra4all region (dead after combine_gx)
  unsigned short* u1b = (unsigned short*)(aggHw + 1600000);  // hop1 aux; aggHw dead after chainC
  float*          aggSS = aggHw + 1600000;                   // phase E (after u1b dead)
  unsigned short* t1b = (unsigned short*)aggHu;              // aggHu dead after chainC
  unsigned short* t2b = (unsigned short*)(aggHu + 1600000);
  unsigned short* t3b = (unsigned short*)aggIN;              // aggIN dead after chainC
  unsigned short* S1b = (unsigned short*)(aggIN + 1600000);  // k_mm_d shadow
  unsigned* payload_vv = (unsigned*)S1;                      // dead after phase A
  unsigned short* u2b  = (unsigned short*)S1;                // hop2 aux; S1 written later by k_mm_d
  int2*     eh         = (int2*)S2;                          // dead after aggB; S2 written by chainC
  int*      srcs_in    = (int*)(S2 + 1600000);

  const int* src_vv = ei_vv;  const int* dst_vv = ei_vv + E_VV;
  const int* src_h  = ei_h;   const int* dst_h  = ei_h + E_H;
  const int* src_in = ei_in;  const int* dst_in = ei_in + E_IN;
  const int* src_ss = ei_ss;  const int* dst_ss = ei_ss + E_SS;

  auto nblk = [](long long n) { return dim3((unsigned)((n + 255) / 256)); };
  const int NB64 = (NSV + 3) / 4;
  const int NB   = (NSV + 63) / 64;
  const int GC   = (ETOT + TC - 1) / TC;

  int* cnt_h  = cnt_all + H_ROW;
  int* cnt_in = cnt_all + IN_ROW;
  int* cnt_ss = cnt_all + SS_ROW;
  int* rs_vv  = rs_all;
  int* rs_h   = rs_all + H_ROW;
  int* rs_in  = rs_all + IN_ROW;
  int* rs_ss  = rs_all + SS_ROW;

  // ---- CSR build (fused) ----
  hipMemsetAsync(bcnt, 0, NBTOT * sizeof(int), stream);
  k_bucket_count<<<GC, 256, 0, stream>>>(dst_vv, dst_h, dst_in, dst_ss, bcnt);
  k_bucket_scan<<<1, 512, 0, stream>>>(bcnt, bbase, cb);
  k_fill_s1_all<<<SB1, 256, 0, stream>>>(src_vv, dst_vv, et_vv, src_h, dst_h, ew_h,
                                         src_in, dst_in, src_ss, dst_ss, cb,
                                         temp_vv, temp_h, temp_in, temp_ss);
  k_fill_s2_all<<<NBTOT, 256, 0, stream>>>(temp_vv, temp_h, temp_in, temp_ss, bbase,
                                           payload_vv, eh, srcs_in, srcs_ss,
                                           rs_all, cnt_all, game_x, x_pad, dinvS);

  // ---- Phase A: v-graph 5-dim ----
  k_vv_pass1<<<nblk(NVV), 256, 0, stream>>>(x_pad, rs_vv, cnt_all, payload_vv, ra4all, h1p);
  k_vv_hop<<<nblk(NVV), 256, 0, stream>>>(h1p, rs_vv, cnt_all, payload_vv, h2p);
  k_vv_hop<<<nblk(NVV), 256, 0, stream>>>(h2p, rs_vv, cnt_all, payload_vv, h3p);
  k_combine_gx<<<dim3((NVV + 31) / 32), 256, 0, stream>>>(x_pad, ra4all, h1p, h2p, h3p,
                                                          W1_rel, W1_root, b1, W12, b12, gx16);

  // ---- Phase B: fused 64-dim bf16 gathers ----
  k_aggB<<<2 * NB64, 256, 0, stream>>>(gx16, rs_h, cnt_h, eh, rs_in, cnt_in, srcs_in,
                                       aggHw, aggHu, aggIN, NB64);

  // ---- Phase C: fused 4-MM chain -> S2 (+ dinv-prescaled bf16 shadow) ----
  k_mm_chainC<<<NB, 256, 0, stream>>>(aggHw, state_x, aggHu, cnt_h, aggIN, cnt_in,
                                      W3_rel, W3_root, b3, W32_l, W32_r, b32,
                                      W4_l, W4_r, b4, W42_l, W42_r, b42,
                                      S2, S2b, dinvS, NSV);

  // ---- Phase D: TAG on s-s (prescaled bf16 hops) + fused quad MM ----
  k_tag64b<<<NB64, 256, 0, stream>>>(S2b, rs_ss, cnt_ss, srcs_ss, dinvS, t1b, u1b, NSV);
  k_tag64b<<<NB64, 256, 0, stream>>>(u1b, rs_ss, cnt_ss, srcs_ss, dinvS, t2b, u2b, NSV);
  k_tag64b<<<NB64, 256, 0, stream>>>(u2b, rs_ss, cnt_ss, srcs_ss, dinvS, t3b, nullptr, NSV);
  k_mm_d<<<NB, 256, 0, stream>>>(S2, t1b, t2b, t3b, W2, b2, S1, S1b, NSV);

  // ---- Phase E: SAGE on s-s + final projection ----
  k_agg64b<<<NB64, 256, 0, stream>>>(S1b, rs_ss, cnt_ss, srcs_ss, aggSS, NSV);
  k_mm_e<<<NB, 256, 0, stream>>>(aggSS, cnt_ss, W5_l, S1, W5_r, b5, Wl, bl, (float*)d_out, NSV);
}